// Round 12
// baseline (128.163 us; speedup 1.0000x reference)
//
#include <hip/hip_runtime.h>
#include <hip/hip_bf16.h>

#define NB 16
#define VOX 884736        // 96*96*96
#define NPTS 4096
#define CHUNK 1024
#define NCHUNK 864        // VOX / CHUNK

typedef _Float16 f16x8 __attribute__((ext_vector_type(8)));
typedef _Float16 f16x4 __attribute__((ext_vector_type(4)));
typedef float f32x4 __attribute__((ext_vector_type(4)));

typedef const __attribute__((address_space(1))) _Float16 gf16;
typedef __attribute__((address_space(3))) _Float16 lf16;
// 16B-per-lane async global->LDS copy: dest = lds base + lane*16 (linear)
#define GLOAD_LDS(gp, lp) __builtin_amdgcn_global_load_lds((gf16*)(gp), (lf16*)(lp), 16, 0, 0)

// packed-fp16 norm + relu on an 8-wide fragment
__device__ __forceinline__ f16x8 nrelu(f16x8 y, f16x8 sc, f16x8 sh) {
    f16x8 r = y * sc + sh;
    #pragma unroll
    for (int e = 0; e < 8; e++) r[e] = (r[e] > (_Float16)0.f) ? r[e] : (_Float16)0.f;
    return r;
}

// ---------------- count + bitmask ----------------

__global__ __launch_bounds__(256) void count_kernel(const float* __restrict__ vol,
                                                    int* __restrict__ counts,
                                                    unsigned long long* __restrict__ bits) {
    int blk = blockIdx.x;  // b*NCHUNK + c
    const float4* v4 = (const float4*)(vol + (size_t)blk * CHUNK);
    float4 v = v4[threadIdx.x];
    int nib = (v.x > 0.5f) | ((v.y > 0.5f) << 1) | ((v.z > 0.5f) << 2) | ((v.w > 0.5f) << 3);
    __shared__ unsigned char nibs[256];
    nibs[threadIdx.x] = (unsigned char)nib;
    int cnt = __popc(nib);
    for (int off = 32; off; off >>= 1) cnt += __shfl_down(cnt, off, 64);
    __shared__ int s[4];
    if ((threadIdx.x & 63) == 0) s[threadIdx.x >> 6] = cnt;
    __syncthreads();
    if (threadIdx.x < 16) {
        unsigned long long wd = 0;
        #pragma unroll
        for (int i = 0; i < 16; i++)
            wd |= (unsigned long long)nibs[threadIdx.x * 16 + i] << (4 * i);
        bits[(size_t)blk * 16 + threadIdx.x] = wd;
    }
    if (threadIdx.x == 0) counts[blk] = s[0] + s[1] + s[2] + s[3];
}

__global__ __launch_bounds__(1024) void scan_kernel(const int* __restrict__ counts,
                                                    int* __restrict__ prefix,
                                                    int* __restrict__ totals) {
    __shared__ int s[1024];
    int b = blockIdx.x, t = threadIdx.x;
    int v = (t < NCHUNK) ? counts[b * NCHUNK + t] : 0;
    s[t] = v;
    __syncthreads();
    for (int off = 1; off < 1024; off <<= 1) {
        int x = (t >= off) ? s[t - off] : 0;
        __syncthreads();
        s[t] += x;
        __syncthreads();
    }
    if (t < NCHUNK) prefix[b * NCHUNK + t] = s[t] - v;   // exclusive
    if (t == NCHUNK - 1) totals[b] = s[t];
}

// ---------------- points via bitmask rank-select, fused conv1 stats ----------------

__global__ __launch_bounds__(256) void points_kernel(const unsigned long long* __restrict__ bits,
                                                     const int* __restrict__ prefix,
                                                     const int* __restrict__ totals,
                                                     const float* __restrict__ w1,
                                                     float* __restrict__ pts,
                                                     float* __restrict__ pstat1) {
    int b = blockIdx.x >> 4;
    int pc = blockIdx.x & 15;
    int p = pc * 256 + threadIdx.x;
    __shared__ int spref[NCHUNK];
    __shared__ float sw1[192];
    for (int i = threadIdx.x; i < NCHUNK; i += 256) spref[i] = prefix[b * NCHUNK + i];
    if (threadIdx.x < 192) sw1[threadIdx.x] = w1[threadIdx.x];
    __syncthreads();
    int n = totals[b];
    float px = 0.f, py = 0.f, pz = 0.f;
    if (n > 0) {
        int k;
        if (n >= NPTS) {
            float t = (float)p * ((float)n - 1.0f);
            t = t / 4095.0f;
            k = (int)t;
            if (k > n - 1) k = n - 1;
            if (k < 0) k = 0;
        } else {
            k = p % n;
        }
        int lo = 0, hi = NCHUNK - 1;
        while (lo < hi) {
            int mid = (lo + hi + 1) >> 1;
            if (spref[mid] <= k) lo = mid; else hi = mid - 1;
        }
        int rr = k - spref[lo];
        const unsigned long long* wb = bits + ((size_t)b * NCHUNK + lo) * 16;
        unsigned long long chosen = 0;
        int wordidx = 0;
        bool found = false;
        #pragma unroll
        for (int w = 0; w < 16; w++) {
            unsigned long long m = wb[w];
            int pcnt = __popcll(m);
            bool take = (!found) && (rr < pcnt);
            if (take) { chosen = m; wordidx = w; found = true; }
            if (!found) rr -= pcnt;
        }
        int pos = 0;
        unsigned long long m64 = chosen;
        int c = __popcll(m64 & 0xFFFFFFFFull);
        if (rr >= c) { pos = 32; rr -= c; m64 >>= 32; }
        unsigned mm = (unsigned)m64;
        c = __popc(mm & 0xFFFFu); if (rr >= c) { pos += 16; rr -= c; mm >>= 16; }
        c = __popc(mm & 0xFFu);   if (rr >= c) { pos += 8;  rr -= c; mm >>= 8; }
        c = __popc(mm & 0xFu);    if (rr >= c) { pos += 4;  rr -= c; mm >>= 4; }
        c = __popc(mm & 0x3u);    if (rr >= c) { pos += 2;  rr -= c; mm >>= 2; }
        c = mm & 1u;              if (rr >= c) { pos += 1; }
        int flat = lo * CHUNK + wordidx * 64 + pos;
        int dd = flat / 9216;           // 96*96
        int rem = flat - dd * 9216;
        int hh = rem / 96;
        int ww = rem - hh * 96;
        px = (float)dd / 95.0f * 2.0f - 1.0f;
        py = (float)hh / 95.0f * 2.0f - 1.0f;
        pz = (float)ww / 95.0f * 2.0f - 1.0f;
    }
    pts[((size_t)b * 3 + 0) * NPTS + p] = px;
    pts[((size_t)b * 3 + 1) * NPTS + p] = py;
    pts[((size_t)b * 3 + 2) * NPTS + p] = pz;
    // fused conv1 GN partial stats
    float s[8] = {}, q[8] = {};
    #pragma unroll
    for (int o = 0; o < 64; o++) {
        float a = sw1[o * 3 + 0] * px + sw1[o * 3 + 1] * py + sw1[o * 3 + 2] * pz;
        s[o >> 3] += a;
        q[o >> 3] += a * a;
    }
    __shared__ float red[4][8][2];
    int wv = threadIdx.x >> 6;
    #pragma unroll
    for (int g = 0; g < 8; g++) {
        float S = s[g], Q = q[g];
        for (int off = 32; off; off >>= 1) {
            S += __shfl_down(S, off, 64);
            Q += __shfl_down(Q, off, 64);
        }
        if ((threadIdx.x & 63) == 0) { red[wv][g][0] = S; red[wv][g][1] = Q; }
    }
    __syncthreads();
    if (threadIdx.x < 8) {
        int g = threadIdx.x;
        float S = red[0][g][0] + red[1][g][0] + red[2][g][0] + red[3][g][0];
        float Q = red[0][g][1] + red[1][g][1] + red[2][g][1] + red[3][g][1];
        float* d = pstat1 + (((size_t)(b * 8 + g)) * 16 + pc) * 2;
        d[0] = S; d[1] = Q;
    }
}

__global__ __launch_bounds__(64) void gn_finalize1(const float* __restrict__ pstat,
                                                   const float* __restrict__ gamma,
                                                   const float* __restrict__ beta,
                                                   float* __restrict__ scale,
                                                   float* __restrict__ shift) {
    int b = blockIdx.x >> 3, g = blockIdx.x & 7;
    const float* base = pstat + (size_t)(b * 8 + g) * 32;
    float S = 0.f, Q = 0.f;
    if (threadIdx.x < 16) { S = base[threadIdx.x * 2]; Q = base[threadIdx.x * 2 + 1]; }
    for (int off = 8; off; off >>= 1) {
        S += __shfl_down(S, off, 64);
        Q += __shfl_down(Q, off, 64);
    }
    __shared__ float ms[2];
    if (threadIdx.x == 0) {
        float inv = 1.0f / (8.0f * 4096.0f);
        float mu = S * inv;
        float var = Q * inv - mu * mu;
        if (var < 0.f) var = 0.f;
        ms[0] = mu; ms[1] = rsqrtf(var + 1e-5f);
    }
    __syncthreads();
    if (threadIdx.x < 8) {
        int c = g * 8 + threadIdx.x;
        float ga = gamma[c] * ms[1];
        scale[b * 64 + c] = ga;
        shift[b * 64 + c] = beta[c] - ms[0] * ga;
    }
}

// ---------------- weight cast: all three -> fragment layout ----------------

__device__ inline void cast_chunk(const float* __restrict__ wf, _Float16* __restrict__ wh,
                                  int CIN, int t) {
    int lane = t & 63;
    int NCB = CIN / 32;
    int cb = (t >> 6) % NCB;
    int ob = t / (64 * NCB);
    int o = ob * 16 + (lane & 15);
    int c0 = cb * 32 + (lane >> 4) * 8;
    const float* src = wf + (size_t)o * CIN + c0;
    f16x8 v;
    #pragma unroll
    for (int e = 0; e < 8; e++) v[e] = (_Float16)src[e];
    *(f16x8*)(wh + (size_t)t * 8) = v;
}

__global__ __launch_bounds__(256) void cast_w_all(const float* __restrict__ w2,
                                                  const float* __restrict__ w3,
                                                  const float* __restrict__ w4,
                                                  _Float16* __restrict__ w2f,
                                                  _Float16* __restrict__ w3f,
                                                  _Float16* __restrict__ w4f) {
    int t = blockIdx.x * 256 + threadIdx.x;
    if (t < 1024) cast_chunk(w2, w2f, 64, t);
    else if (t < 1024 + 4096) cast_chunk(w3, w3f, 128, t - 1024);
    else if (t < 1024 + 4096 + 16384) cast_chunk(w4, w4f, 256, t - 5120);
}

// ---------------- fused layer 2: conv1+GN+ReLU stage (LDS) -> swapped GEMM ----------------
// swapped mfma(W,X): D: o = (l>>4)*4+j (in-lane), p = l&15 (across lanes)
// -> y2 stored directly in A-fragment layout [p16][cb=4][lane][8].

__global__ __launch_bounds__(256, 4) void fused_l2(const float* __restrict__ pts,
                                                   const float* __restrict__ w1,
                                                   const float* __restrict__ scale,
                                                   const float* __restrict__ shift,
                                                   const _Float16* __restrict__ wfrag,
                                                   _Float16* __restrict__ y2,
                                                   float* __restrict__ pstat) {
    __shared__ _Float16 sl[64 * 64];
    __shared__ float sw1[192], ssc[64], ssh[64];
    int b = blockIdx.y, pblk = blockIdx.x, tid = threadIdx.x;
    if (tid < 192) sw1[tid] = w1[tid];
    if (tid < 64) { ssc[tid] = scale[b * 64 + tid]; ssh[tid] = shift[b * 64 + tid]; }
    __syncthreads();
    {   // stage: recompute conv1 + norm + relu -> swizzled LDS (slot = ch ^ (p&7))
        int p = tid >> 2, qo = (tid & 3) * 16;
        int pg = pblk * 64 + p;
        float x0 = pts[((size_t)b * 3 + 0) * NPTS + pg];
        float x1 = pts[((size_t)b * 3 + 1) * NPTS + pg];
        float x2 = pts[((size_t)b * 3 + 2) * NPTS + pg];
        #pragma unroll
        for (int e = 0; e < 16; e++) {
            int o = qo + e;
            float a = sw1[o * 3 + 0] * x0 + sw1[o * 3 + 1] * x1 + sw1[o * 3 + 2] * x2;
            float r = fmaxf(a * ssc[o] + ssh[o], 0.f);
            sl[p * 64 + (((o >> 3) ^ (p & 7)) << 3) + (o & 7)] = (_Float16)r;
        }
    }
    __syncthreads();
    int wv = tid >> 6, lane = tid & 63, lr = lane & 15, lk = lane >> 4;
    int ph = wv & 1, oh = wv >> 1;
    int Pg = b * 64 + pblk;
    int pb32 = (Pg << 1) | ph;
    int P16 = Pg * 4 + ph * 2;
    f32x4 acc[2][4] = {};
    #pragma unroll
    for (int cb = 0; cb < 2; cb++) {
        int ch = cb * 4 + lk;
        f16x8 af0, af1;
        {
            int p0 = ph * 32 + lr;
            af0 = *(const f16x8*)(sl + p0 * 64 + ((ch ^ (p0 & 7)) << 3));
            int p1 = p0 + 16;
            af1 = *(const f16x8*)(sl + p1 * 64 + ((ch ^ (p1 & 7)) << 3));
        }
        #pragma unroll
        for (int i = 0; i < 4; i++) {
            int ofr = oh * 4 + i;
            f16x8 bf = *(const f16x8*)(wfrag + (((size_t)ofr * 2 + cb) * 64 + lane) * 8);
            acc[0][i] = __builtin_amdgcn_mfma_f32_16x16x32_f16(bf, af0, acc[0][i], 0, 0, 0);
            acc[1][i] = __builtin_amdgcn_mfma_f32_16x16x32_f16(bf, af1, acc[1][i], 0, 0, 0);
        }
    }
    #pragma unroll
    for (int i = 0; i < 4; i++) {
        int ofr = oh * 4 + i;
        int cb2 = ofr >> 1;
        int kg = (ofr & 1) * 2 + (lk >> 1);
        int lanep = lr + 16 * kg;
        int sub = lk & 1;
        #pragma unroll
        for (int pf = 0; pf < 2; pf++) {
            f16x4 vv;
            #pragma unroll
            for (int j = 0; j < 4; j++) vv[j] = (_Float16)acc[pf][i][j];
            *(f16x4*)(y2 + (((size_t)(P16 + pf) * 4 + cb2) * 64 + lanep) * 8 + sub * 4) = vv;
        }
        float s[4], q[4];
        #pragma unroll
        for (int j = 0; j < 4; j++) {
            float a0 = acc[0][i][j], a1 = acc[1][i][j];
            s[j] = a0 + a1; q[j] = a0 * a0 + a1 * a1;
        }
        #pragma unroll
        for (int m = 1; m <= 8; m <<= 1)
            #pragma unroll
            for (int j = 0; j < 4; j++) {
                s[j] += __shfl_xor(s[j], m, 64);
                q[j] += __shfl_xor(q[j], m, 64);
            }
        if (lr == 0) {
            int o0 = ofr * 16 + lk * 4;
            float* d = pstat + ((size_t)pb32 * 128 + o0) * 2;
            *(float4*)d = make_float4(s[0], q[0], s[1], q[1]);
            *(float4*)(d + 4) = make_float4(s[2], q[2], s[3], q[3]);
        }
    }
}

// ---------------- fused layer 3: DMA-staged A + in-reg norm, swapped GEMM ----------------
// y2 A-layout tile (16 KB contiguous) staged via global_load_lds; fragment read is
// lane-identity (conflict-free ds_read_b128); GN+ReLU applied post-read in pk-fp16.

__global__ __launch_bounds__(256, 4) void fused_l3(const _Float16* __restrict__ y2,
                                                   const _Float16* __restrict__ sch2,
                                                   const _Float16* __restrict__ shh2,
                                                   const _Float16* __restrict__ w3f,
                                                   _Float16* __restrict__ y3,
                                                   float* __restrict__ pstat) {
    __shared__ _Float16 sl[64 * 128];    // 16 KB A-layout tile
    int b = blockIdx.y, pblk = blockIdx.x, tid = threadIdx.x;
    int wv = tid >> 6, lane = tid & 63, lr = lane & 15, lk = lane >> 4;
    int Pg = b * 64 + pblk;
    const _Float16* yt = y2 + (size_t)Pg * 64 * 128;
    #pragma unroll
    for (int i = 0; i < 4; i++) {
        int off = (wv * 4 + i) * 512;    // 1 KB per instruction
        GLOAD_LDS(yt + off + lane * 8, sl + off);
    }
    const _Float16* sch = sch2 + b * 128;
    const _Float16* shh = shh2 + b * 128;
    f16x8 scv[4], shv[4];
    #pragma unroll
    for (int cb = 0; cb < 4; cb++) {
        scv[cb] = *(const f16x8*)(sch + cb * 32 + lk * 8);
        shv[cb] = *(const f16x8*)(shh + cb * 32 + lk * 8);
    }
    __syncthreads();
    int ph = wv & 1, oh = wv >> 1;
    int pb32 = (Pg << 1) | ph;
    int P16 = Pg * 4 + ph * 2;
    #pragma unroll
    for (int ck = 0; ck < 2; ck++) {
        f32x4 acc[2][4] = {};
        #pragma unroll
        for (int cb = 0; cb < 4; cb++) {
            f16x8 af0 = nrelu(*(const f16x8*)(sl + (((ph * 2 + 0) * 4 + cb) * 64 + lane) * 8), scv[cb], shv[cb]);
            f16x8 af1 = nrelu(*(const f16x8*)(sl + (((ph * 2 + 1) * 4 + cb) * 64 + lane) * 8), scv[cb], shv[cb]);
            #pragma unroll
            for (int i = 0; i < 4; i++) {
                int ofr = oh * 8 + ck * 4 + i;
                f16x8 bf = *(const f16x8*)(w3f + (((size_t)ofr * 4 + cb) * 64 + lane) * 8);
                acc[0][i] = __builtin_amdgcn_mfma_f32_16x16x32_f16(bf, af0, acc[0][i], 0, 0, 0);
                acc[1][i] = __builtin_amdgcn_mfma_f32_16x16x32_f16(bf, af1, acc[1][i], 0, 0, 0);
            }
        }
        #pragma unroll
        for (int i = 0; i < 4; i++) {
            int ofr = oh * 8 + ck * 4 + i;
            int cb3 = ofr >> 1;
            int kg = (ofr & 1) * 2 + (lk >> 1);
            int lanep = lr + 16 * kg;
            int sub = lk & 1;
            #pragma unroll
            for (int pf = 0; pf < 2; pf++) {
                f16x4 vv;
                #pragma unroll
                for (int j = 0; j < 4; j++) vv[j] = (_Float16)acc[pf][i][j];
                *(f16x4*)(y3 + (((size_t)(P16 + pf) * 8 + cb3) * 64 + lanep) * 8 + sub * 4) = vv;
            }
            float s[4], q[4];
            #pragma unroll
            for (int j = 0; j < 4; j++) {
                float a0 = acc[0][i][j], a1 = acc[1][i][j];
                s[j] = a0 + a1; q[j] = a0 * a0 + a1 * a1;
            }
            #pragma unroll
            for (int m = 1; m <= 8; m <<= 1)
                #pragma unroll
                for (int j = 0; j < 4; j++) {
                    s[j] += __shfl_xor(s[j], m, 64);
                    q[j] += __shfl_xor(q[j], m, 64);
                }
            if (lr == 0) {
                int o0 = ofr * 16 + lk * 4;
                float* d = pstat + ((size_t)pb32 * 256 + o0) * 2;
                *(float4*)d = make_float4(s[0], q[0], s[1], q[1]);
                *(float4*)(d + 4) = make_float4(s[2], q[2], s[3], q[3]);
            }
        }
    }
}

// ---------------- fused layer 4: DMA-staged A + in-reg norm, non-swapped, POOL ----------------

__global__ __launch_bounds__(256, 4) void fused_l4(const _Float16* __restrict__ y3,
                                                   const _Float16* __restrict__ sch3,
                                                   const _Float16* __restrict__ shh3,
                                                   const _Float16* __restrict__ w4f,
                                                   float* __restrict__ pstat4) {
    __shared__ _Float16 sl[64 * 256];    // 32 KB A-layout tile
    __shared__ _Float16 sscsh[512];      // [0..255]=scale, [256..511]=shift
    int b = blockIdx.y, pblk = blockIdx.x, tid = threadIdx.x;
    int wv = tid >> 6, lane = tid & 63, lr = lane & 15, lk = lane >> 4;
    int Pg = b * 64 + pblk;
    const _Float16* yt = y3 + (size_t)Pg * 64 * 256;
    #pragma unroll
    for (int i = 0; i < 8; i++) {
        int off = (wv * 8 + i) * 512;    // 1 KB per instruction
        GLOAD_LDS(yt + off + lane * 8, sl + off);
    }
    sscsh[tid] = sch3[b * 256 + tid];
    sscsh[256 + tid] = shh3[b * 256 + tid];
    __syncthreads();
    int ph = wv & 1, oh = wv >> 1;
    int pb32 = (Pg << 1) | ph;
    #pragma unroll
    for (int ck = 0; ck < 4; ck++) {
        f32x4 acc[2][4] = {};
        #pragma unroll
        for (int cb = 0; cb < 8; cb++) {
            f16x8 scv = *(const f16x8*)(sscsh + cb * 32 + lk * 8);
            f16x8 shv = *(const f16x8*)(sscsh + 256 + cb * 32 + lk * 8);
            f16x8 af0 = nrelu(*(const f16x8*)(sl + (((ph * 2 + 0) * 8 + cb) * 64 + lane) * 8), scv, shv);
            f16x8 af1 = nrelu(*(const f16x8*)(sl + (((ph * 2 + 1) * 8 + cb) * 64 + lane) * 8), scv, shv);
            #pragma unroll
            for (int i = 0; i < 4; i++) {
                int ofr = oh * 16 + ck * 4 + i;
                f16x8 bf = *(const f16x8*)(w4f + (((size_t)ofr * 8 + cb) * 64 + lane) * 8);
                acc[0][i] = __builtin_amdgcn_mfma_f32_16x16x32_f16(af0, bf, acc[0][i], 0, 0, 0);
                acc[1][i] = __builtin_amdgcn_mfma_f32_16x16x32_f16(af1, bf, acc[1][i], 0, 0, 0);
            }
        }
        #pragma unroll
        for (int i = 0; i < 4; i++) {
            int ofr = oh * 16 + ck * 4 + i;
            float S = 0.f, Q = 0.f, MX = -1e30f, MN = 1e30f;
            #pragma unroll
            for (int pf = 0; pf < 2; pf++)
                #pragma unroll
                for (int j = 0; j < 4; j++) {
                    float v = acc[pf][i][j];
                    S += v; Q += v * v;
                    MX = fmaxf(MX, v); MN = fminf(MN, v);
                }
            S += __shfl_xor(S, 16, 64); Q += __shfl_xor(Q, 16, 64);
            MX = fmaxf(MX, __shfl_xor(MX, 16, 64)); MN = fminf(MN, __shfl_xor(MN, 16, 64));
            S += __shfl_xor(S, 32, 64); Q += __shfl_xor(Q, 32, 64);
            MX = fmaxf(MX, __shfl_xor(MX, 32, 64)); MN = fminf(MN, __shfl_xor(MN, 32, 64));
            if (lk == 0) {
                int o = ofr * 16 + lr;
                *(float4*)(pstat4 + ((size_t)pb32 * 512 + o) * 4) = make_float4(S, Q, MX, MN);
            }
        }
    }
}

// ---------------- GN finalize (layers 2,3): pstat[b][128][C][2] -> fp16 scale/shift ----------------

template <int C>
__global__ __launch_bounds__(256) void gn_finalizeG(const float* __restrict__ pstat,
                                                    const float* __restrict__ gamma,
                                                    const float* __restrict__ beta,
                                                    _Float16* __restrict__ scaleh,
                                                    _Float16* __restrict__ shifth) {
    constexpr int GS = C / 8;
    int b = blockIdx.x >> 3, g = blockIdx.x & 7;
    const float* base = pstat + (size_t)b * 128 * C * 2;
    float S = 0.f, Q = 0.f;
    for (int i = threadIdx.x; i < 128 * GS; i += 256) {
        int pb = i / GS;
        int c = g * GS + (i % GS);
        const float* d = base + ((size_t)pb * C + c) * 2;
        S += d[0]; Q += d[1];
    }
    for (int off = 32; off; off >>= 1) {
        S += __shfl_down(S, off, 64);
        Q += __shfl_down(Q, off, 64);
    }
    __shared__ float ss[8];
    if ((threadIdx.x & 63) == 0) {
        ss[(threadIdx.x >> 6) * 2] = S;
        ss[(threadIdx.x >> 6) * 2 + 1] = Q;
    }
    __syncthreads();
    __shared__ float ms[2];
    if (threadIdx.x == 0) {
        float St = ss[0] + ss[2] + ss[4] + ss[6];
        float Qt = ss[1] + ss[3] + ss[5] + ss[7];
        float inv = 1.0f / ((float)GS * 4096.0f);
        float mu = St * inv;
        float var = Qt * inv - mu * mu;
        if (var < 0.f) var = 0.f;
        ms[0] = mu; ms[1] = rsqrtf(var + 1e-5f);
    }
    __syncthreads();
    for (int i = threadIdx.x; i < GS; i += 256) {
        int c = g * GS + i;
        float ga = gamma[c] * ms[1];
        scaleh[(size_t)b * C + c] = (_Float16)ga;
        shifth[(size_t)b * C + c] = (_Float16)(beta[c] - ms[0] * ga);
    }
}

// ---------------- pool finalize (coalesced): pstat4[b][128][512][4] -> g[b][512] ----------------

__global__ __launch_bounds__(256) void pool_final(const float* __restrict__ pstat4,
                                                  const float* __restrict__ gamma,
                                                  const float* __restrict__ beta,
                                                  float* __restrict__ g) {
    int b = blockIdx.x >> 3, gr = blockIdx.x & 7;
    int ch = threadIdx.x & 63;
    int pg = threadIdx.x >> 6;          // 4 pb-subgroups
    int o = gr * 64 + ch;
    float S = 0.f, Q = 0.f, MX = -1e30f, MN = 1e30f;
    for (int pb = pg; pb < 128; pb += 4) {
        float4 v = *(const float4*)(pstat4 + (((size_t)(b * 128 + pb)) * 512 + o) * 4);
        S += v.x; Q += v.y; MX = fmaxf(MX, v.z); MN = fminf(MN, v.w);
    }
    __shared__ float sS[4][64], sQ[4][64], sMX[4][64], sMN[4][64];
    sS[pg][ch] = S; sQ[pg][ch] = Q; sMX[pg][ch] = MX; sMN[pg][ch] = MN;
    __syncthreads();
    if (threadIdx.x < 64) {
        float Sc = sS[0][ch] + sS[1][ch] + sS[2][ch] + sS[3][ch];
        float Qc = sQ[0][ch] + sQ[1][ch] + sQ[2][ch] + sQ[3][ch];
        float MXc = fmaxf(fmaxf(sMX[0][ch], sMX[1][ch]), fmaxf(sMX[2][ch], sMX[3][ch]));
        float MNc = fminf(fminf(sMN[0][ch], sMN[1][ch]), fminf(sMN[2][ch], sMN[3][ch]));
        float St = Sc, Qt = Qc;
        for (int off = 32; off; off >>= 1) {
            St += __shfl_xor(St, off, 64);
            Qt += __shfl_xor(Qt, off, 64);
        }
        float inv = 1.0f / (64.0f * 4096.0f);
        float mu = St * inv;
        float var = Qt * inv - mu * mu;
        if (var < 0.f) var = 0.f;
        float rstd = rsqrtf(var + 1e-5f);
        float sc = gamma[o] * rstd;
        float sh = beta[o] - mu * sc;
        float m = (sc >= 0.f ? MXc : MNc) * sc + sh;
        g[b * 512 + o] = fmaxf(m, 0.f);
    }
}

// ---------------- FC head ----------------

__global__ __launch_bounds__(128) void head_kernel(const float* __restrict__ g,
                                                   const float* __restrict__ fc1w,
                                                   const float* __restrict__ fc1b,
                                                   const float* __restrict__ fc2w,
                                                   const float* __restrict__ fc2b,
                                                   float* __restrict__ out) {
    int b = blockIdx.x;
    int o = threadIdx.x;   // 128
    __shared__ float sg[512];
    for (int i = threadIdx.x; i < 512; i += 128) sg[i] = g[b * 512 + i];
    __syncthreads();
    float acc = fc1b[o];
    for (int c = 0; c < 512; c++) acc += sg[c] * fc1w[o * 512 + c];
    float h = fmaxf(acc, 0.f) * fc2w[o];
    for (int off = 32; off; off >>= 1) h += __shfl_down(h, off, 64);
    __shared__ float s2[2];
    if ((threadIdx.x & 63) == 0) s2[threadIdx.x >> 6] = h;
    __syncthreads();
    if (threadIdx.x == 0) out[b] = s2[0] + s2[1] + fc2b[0];
}

// ---------------- launch ----------------

extern "C" void kernel_launch(void* const* d_in, const int* in_sizes, int n_in,
                              void* d_out, int out_size, void* d_ws, size_t ws_size,
                              hipStream_t stream) {
    const float* vol  = (const float*)d_in[0];
    const float* w1   = (const float*)d_in[1];
    const float* gn1w = (const float*)d_in[2];
    const float* gn1b = (const float*)d_in[3];
    const float* w2   = (const float*)d_in[4];
    const float* gn2w = (const float*)d_in[5];
    const float* gn2b = (const float*)d_in[6];
    const float* w3   = (const float*)d_in[7];
    const float* gn3w = (const float*)d_in[8];
    const float* gn3b = (const float*)d_in[9];
    const float* w4   = (const float*)d_in[10];
    const float* gn4w = (const float*)d_in[11];
    const float* gn4b = (const float*)d_in[12];
    const float* fc1w = (const float*)d_in[13];
    const float* fc1b = (const float*)d_in[14];
    const float* fc2w = (const float*)d_in[15];
    const float* fc2b = (const float*)d_in[16];
    float* out = (float*)d_out;

    char* ws = (char*)d_ws;
    size_t cur = 0;
    auto alloc = [&](size_t bytes) -> void* {
        cur = (cur + 255) & ~(size_t)255;
        void* p = ws + cur;
        cur += bytes;
        return p;
    };
    int*      counts  = (int*)alloc((size_t)NB * NCHUNK * 4);
    int*      prefix  = (int*)alloc((size_t)NB * NCHUNK * 4);
    int*      totals  = (int*)alloc(64);
    unsigned long long* bits = (unsigned long long*)alloc((size_t)NB * NCHUNK * 16 * 8);
    float*    pts     = (float*)alloc((size_t)NB * 3 * NPTS * 4);
    float*    gbuf    = (float*)alloc((size_t)NB * 512 * 4);
    float*    pstat1  = (float*)alloc((size_t)NB * 8 * 16 * 2 * 4);
    float*    pstatG  = (float*)alloc((size_t)NB * 128 * 256 * 2 * 4);
    float*    pstat4  = (float*)alloc((size_t)NB * 128 * 512 * 4 * 4);
    float*    scale1  = (float*)alloc((size_t)NB * 64 * 4);
    float*    shift1  = (float*)alloc((size_t)NB * 64 * 4);
    _Float16* sc2h    = (_Float16*)alloc((size_t)NB * 128 * 2);
    _Float16* sh2h    = (_Float16*)alloc((size_t)NB * 128 * 2);
    _Float16* sc3h    = (_Float16*)alloc((size_t)NB * 256 * 2);
    _Float16* sh3h    = (_Float16*)alloc((size_t)NB * 256 * 2);
    _Float16* w2f     = (_Float16*)alloc((size_t)128 * 64 * 2);
    _Float16* w3f     = (_Float16*)alloc((size_t)256 * 128 * 2);
    _Float16* w4f     = (_Float16*)alloc((size_t)512 * 256 * 2);
    _Float16* y2      = (_Float16*)alloc((size_t)NB * NPTS * 128 * 2);
    _Float16* y3      = (_Float16*)alloc((size_t)NB * NPTS * 256 * 2);

    // 1. mask/count/scan, then points + fused conv1 stats
    count_kernel<<<dim3(NB * NCHUNK), dim3(256), 0, stream>>>(vol, counts, bits);
    scan_kernel<<<dim3(NB), dim3(1024), 0, stream>>>(counts, prefix, totals);
    points_kernel<<<dim3(NB * 16), dim3(256), 0, stream>>>(bits, prefix, totals, w1, pts, pstat1);

    // 2. weight casts
    cast_w_all<<<dim3(84), dim3(256), 0, stream>>>(w2, w3, w4, w2f, w3f, w4f);

    // 3. layer-1 finalize, then fused layer 2 (conv1 recompute + swapped GEMM -> y2 A-layout)
    gn_finalize1<<<dim3(NB * 8), dim3(64), 0, stream>>>(pstat1, gn1w, gn1b, scale1, shift1);
    fused_l2<<<dim3(64, NB), dim3(256), 0, stream>>>(pts, w1, scale1, shift1, w2f, y2, pstatG);

    // 4. layer 3: DMA-staged tile + in-register norm, swapped GEMM -> y3 A-layout
    gn_finalizeG<128><<<dim3(NB * 8), dim3(256), 0, stream>>>(pstatG, gn2w, gn2b, sc2h, sh2h);
    fused_l3<<<dim3(64, NB), dim3(256), 0, stream>>>(y2, sc2h, sh2h, w3f, y3, pstatG);

    // 5. layer 4: DMA-staged tile + in-register norm, pooled epilogue (no y4)
    gn_finalizeG<256><<<dim3(NB * 8), dim3(256), 0, stream>>>(pstatG, gn3w, gn3b, sc3h, sh3h);
    fused_l4<<<dim3(64, NB), dim3(256), 0, stream>>>(y3, sc3h, sh3h, w4f, pstat4);

    // 6. pool finalize + head
    pool_final<<<dim3(NB * 8), dim3(256), 0, stream>>>(pstat4, gn4w, gn4b, gbuf);
    head_kernel<<<dim3(NB), dim3(128), 0, stream>>>(gbuf, fc1w, fc1b, fc2w, fc2b, out);
}

// Round 13
// 125.527 us; speedup vs baseline: 1.0210x; 1.0210x over previous
//
#include <hip/hip_runtime.h>
#include <hip/hip_bf16.h>

#define NB 16
#define VOX 884736        // 96*96*96
#define NPTS 4096
#define CHUNK 1024
#define NCHUNK 864        // VOX / CHUNK

typedef _Float16 f16x8 __attribute__((ext_vector_type(8)));
typedef _Float16 f16x4 __attribute__((ext_vector_type(4)));
typedef float f32x4 __attribute__((ext_vector_type(4)));

typedef const __attribute__((address_space(1))) _Float16 gf16;
typedef __attribute__((address_space(3))) _Float16 lf16;
// 16B-per-lane async global->LDS copy: dest = lds base + lane*16 (linear)
#define GLOAD_LDS(gp, lp) __builtin_amdgcn_global_load_lds((gf16*)(gp), (lf16*)(lp), 16, 0, 0)

// packed-fp16 norm + relu on an 8-wide fragment
__device__ __forceinline__ f16x8 nrelu(f16x8 y, f16x8 sc, f16x8 sh) {
    f16x8 r = y * sc + sh;
    #pragma unroll
    for (int e = 0; e < 8; e++) r[e] = (r[e] > (_Float16)0.f) ? r[e] : (_Float16)0.f;
    return r;
}

// ---------------- weight cast helper ----------------

__device__ inline void cast_chunk(const float* __restrict__ wf, _Float16* __restrict__ wh,
                                  int CIN, int t) {
    int lane = t & 63;
    int NCB = CIN / 32;
    int cb = (t >> 6) % NCB;
    int ob = t / (64 * NCB);
    int o = ob * 16 + (lane & 15);
    int c0 = cb * 32 + (lane >> 4) * 8;
    const float* src = wf + (size_t)o * CIN + c0;
    f16x8 v;
    #pragma unroll
    for (int e = 0; e < 8; e++) v[e] = (_Float16)src[e];
    *(f16x8*)(wh + (size_t)t * 8) = v;
}

// ---------------- count + bitmask  (+ appended weight-cast blocks) ----------------

__global__ __launch_bounds__(256) void count_cast_kernel(const float* __restrict__ vol,
                                                         int* __restrict__ counts,
                                                         unsigned long long* __restrict__ bits,
                                                         const float* __restrict__ w2,
                                                         const float* __restrict__ w3,
                                                         const float* __restrict__ w4,
                                                         _Float16* __restrict__ w2f,
                                                         _Float16* __restrict__ w3f,
                                                         _Float16* __restrict__ w4f) {
    if (blockIdx.x >= NB * NCHUNK) {
        int t = (blockIdx.x - NB * NCHUNK) * 256 + threadIdx.x;
        if (t < 1024) cast_chunk(w2, w2f, 64, t);
        else if (t < 1024 + 4096) cast_chunk(w3, w3f, 128, t - 1024);
        else if (t < 1024 + 4096 + 16384) cast_chunk(w4, w4f, 256, t - 5120);
        return;
    }
    int blk = blockIdx.x;  // b*NCHUNK + c
    const float4* v4 = (const float4*)(vol + (size_t)blk * CHUNK);
    float4 v = v4[threadIdx.x];
    int nib = (v.x > 0.5f) | ((v.y > 0.5f) << 1) | ((v.z > 0.5f) << 2) | ((v.w > 0.5f) << 3);
    __shared__ unsigned char nibs[256];
    nibs[threadIdx.x] = (unsigned char)nib;
    int cnt = __popc(nib);
    for (int off = 32; off; off >>= 1) cnt += __shfl_down(cnt, off, 64);
    __shared__ int s[4];
    if ((threadIdx.x & 63) == 0) s[threadIdx.x >> 6] = cnt;
    __syncthreads();
    if (threadIdx.x < 16) {
        unsigned long long wd = 0;
        #pragma unroll
        for (int i = 0; i < 16; i++)
            wd |= (unsigned long long)nibs[threadIdx.x * 16 + i] << (4 * i);
        bits[(size_t)blk * 16 + threadIdx.x] = wd;
    }
    if (threadIdx.x == 0) counts[blk] = s[0] + s[1] + s[2] + s[3];
}

// ---------------- points: inline scan + bitmask rank-select + fused conv1 stats ----------------

__global__ __launch_bounds__(256) void points_kernel(const unsigned long long* __restrict__ bits,
                                                     const int* __restrict__ counts,
                                                     const float* __restrict__ w1,
                                                     float* __restrict__ pts,
                                                     float* __restrict__ pstat1) {
    int b = blockIdx.x >> 4;
    int pc = blockIdx.x & 15;
    int p = pc * 256 + threadIdx.x;
    int tid = threadIdx.x;
    __shared__ int sdat[NCHUNK];
    __shared__ float sw1[192];
    __shared__ int wsum[4];
    for (int i = tid; i < NCHUNK; i += 256) sdat[i] = counts[b * NCHUNK + i];
    if (tid < 192) sw1[tid] = w1[tid];
    __syncthreads();
    // in-block exclusive scan of sdat[0..863]
    int i0 = tid * 4;
    int v0 = (i0 + 0 < NCHUNK) ? sdat[i0 + 0] : 0;
    int v1 = (i0 + 1 < NCHUNK) ? sdat[i0 + 1] : 0;
    int v2 = (i0 + 2 < NCHUNK) ? sdat[i0 + 2] : 0;
    int v3 = (i0 + 3 < NCHUNK) ? sdat[i0 + 3] : 0;
    int l3 = v0 + v1 + v2 + v3;
    int lane = tid & 63, wv = tid >> 6;
    int a = l3;
    #pragma unroll
    for (int off = 1; off < 64; off <<= 1) {
        int x = __shfl_up(a, off, 64);
        if (lane >= off) a += x;
    }
    if (lane == 63) wsum[wv] = a;
    __syncthreads();
    int woff = 0;
    #pragma unroll
    for (int w = 0; w < 4; w++) if (w < wv) woff += wsum[w];
    a += woff;
    int excl = a - l3;
    int n = wsum[0] + wsum[1] + wsum[2] + wsum[3];
    __syncthreads();
    if (i0 + 0 < NCHUNK) sdat[i0 + 0] = excl;
    if (i0 + 1 < NCHUNK) sdat[i0 + 1] = excl + v0;
    if (i0 + 2 < NCHUNK) sdat[i0 + 2] = excl + v0 + v1;
    if (i0 + 3 < NCHUNK) sdat[i0 + 3] = excl + v0 + v1 + v2;
    __syncthreads();
    float px = 0.f, py = 0.f, pz = 0.f;
    if (n > 0) {
        int k;
        if (n >= NPTS) {
            float t = (float)p * ((float)n - 1.0f);
            t = t / 4095.0f;
            k = (int)t;
            if (k > n - 1) k = n - 1;
            if (k < 0) k = 0;
        } else {
            k = p % n;
        }
        int lo = 0, hi = NCHUNK - 1;
        while (lo < hi) {
            int mid = (lo + hi + 1) >> 1;
            if (sdat[mid] <= k) lo = mid; else hi = mid - 1;
        }
        int rr = k - sdat[lo];
        const unsigned long long* wb = bits + ((size_t)b * NCHUNK + lo) * 16;
        unsigned long long chosen = 0;
        int wordidx = 0;
        bool found = false;
        #pragma unroll
        for (int w = 0; w < 16; w++) {
            unsigned long long m = wb[w];
            int pcnt = __popcll(m);
            bool take = (!found) && (rr < pcnt);
            if (take) { chosen = m; wordidx = w; found = true; }
            if (!found) rr -= pcnt;
        }
        int pos = 0;
        unsigned long long m64 = chosen;
        int c = __popcll(m64 & 0xFFFFFFFFull);
        if (rr >= c) { pos = 32; rr -= c; m64 >>= 32; }
        unsigned mm = (unsigned)m64;
        c = __popc(mm & 0xFFFFu); if (rr >= c) { pos += 16; rr -= c; mm >>= 16; }
        c = __popc(mm & 0xFFu);   if (rr >= c) { pos += 8;  rr -= c; mm >>= 8; }
        c = __popc(mm & 0xFu);    if (rr >= c) { pos += 4;  rr -= c; mm >>= 4; }
        c = __popc(mm & 0x3u);    if (rr >= c) { pos += 2;  rr -= c; mm >>= 2; }
        c = mm & 1u;              if (rr >= c) { pos += 1; }
        int flat = lo * CHUNK + wordidx * 64 + pos;
        int dd = flat / 9216;           // 96*96
        int rem = flat - dd * 9216;
        int hh = rem / 96;
        int ww = rem - hh * 96;
        px = (float)dd / 95.0f * 2.0f - 1.0f;
        py = (float)hh / 95.0f * 2.0f - 1.0f;
        pz = (float)ww / 95.0f * 2.0f - 1.0f;
    }
    pts[((size_t)b * 3 + 0) * NPTS + p] = px;
    pts[((size_t)b * 3 + 1) * NPTS + p] = py;
    pts[((size_t)b * 3 + 2) * NPTS + p] = pz;
    // fused conv1 GN partial stats
    float s[8] = {}, q[8] = {};
    #pragma unroll
    for (int o = 0; o < 64; o++) {
        float av = sw1[o * 3 + 0] * px + sw1[o * 3 + 1] * py + sw1[o * 3 + 2] * pz;
        s[o >> 3] += av;
        q[o >> 3] += av * av;
    }
    __shared__ float red[4][8][2];
    #pragma unroll
    for (int g = 0; g < 8; g++) {
        float S = s[g], Q = q[g];
        for (int off = 32; off; off >>= 1) {
            S += __shfl_down(S, off, 64);
            Q += __shfl_down(Q, off, 64);
        }
        if ((threadIdx.x & 63) == 0) { red[wv][g][0] = S; red[wv][g][1] = Q; }
    }
    __syncthreads();
    if (tid < 8) {
        int g = tid;
        float S = red[0][g][0] + red[1][g][0] + red[2][g][0] + red[3][g][0];
        float Q = red[0][g][1] + red[1][g][1] + red[2][g][1] + red[3][g][1];
        float* d = pstat1 + (((size_t)(b * 8 + g)) * 16 + pc) * 2;
        d[0] = S; d[1] = Q;
    }
}

// ---------------- fused layer 2: inline GN1 finalize + conv1 stage + swapped GEMM ----------------

__global__ __launch_bounds__(256, 4) void fused_l2(const float* __restrict__ pts,
                                                   const float* __restrict__ w1,
                                                   const float* __restrict__ pstat1,
                                                   const float* __restrict__ gn1w,
                                                   const float* __restrict__ gn1b,
                                                   const _Float16* __restrict__ wfrag,
                                                   _Float16* __restrict__ y2,
                                                   float* __restrict__ pstat) {
    __shared__ _Float16 sl[64 * 64];
    __shared__ float sw1[192], ssc[64], ssh[64], ms1[8][2];
    int b = blockIdx.y, pblk = blockIdx.x, tid = threadIdx.x;
    if (tid < 192) sw1[tid] = w1[tid];
    if (tid < 8) {
        const float* pbase = pstat1 + (size_t)(b * 8 + tid) * 32;
        float S = 0.f, Q = 0.f;
        #pragma unroll
        for (int pc = 0; pc < 16; pc++) { S += pbase[2 * pc]; Q += pbase[2 * pc + 1]; }
        float inv = 1.0f / (8.0f * 4096.0f);
        float mu = S * inv;
        float var = Q * inv - mu * mu;
        if (var < 0.f) var = 0.f;
        ms1[tid][0] = mu; ms1[tid][1] = rsqrtf(var + 1e-5f);
    }
    __syncthreads();
    if (tid < 64) {
        int g = tid >> 3;
        float ga = gn1w[tid] * ms1[g][1];
        ssc[tid] = ga;
        ssh[tid] = gn1b[tid] - ms1[g][0] * ga;
    }
    __syncthreads();
    {   // stage: recompute conv1 + norm + relu -> swizzled LDS (slot = ch ^ (p&7))
        int p = tid >> 2, qo = (tid & 3) * 16;
        int pg = pblk * 64 + p;
        float x0 = pts[((size_t)b * 3 + 0) * NPTS + pg];
        float x1 = pts[((size_t)b * 3 + 1) * NPTS + pg];
        float x2 = pts[((size_t)b * 3 + 2) * NPTS + pg];
        #pragma unroll
        for (int e = 0; e < 16; e++) {
            int o = qo + e;
            float a = sw1[o * 3 + 0] * x0 + sw1[o * 3 + 1] * x1 + sw1[o * 3 + 2] * x2;
            float r = fmaxf(a * ssc[o] + ssh[o], 0.f);
            sl[p * 64 + (((o >> 3) ^ (p & 7)) << 3) + (o & 7)] = (_Float16)r;
        }
    }
    __syncthreads();
    int wv = tid >> 6, lane = tid & 63, lr = lane & 15, lk = lane >> 4;
    int ph = wv & 1, oh = wv >> 1;
    int Pg = b * 64 + pblk;
    int pb32 = (Pg << 1) | ph;
    int P16 = Pg * 4 + ph * 2;
    f32x4 acc[2][4] = {};
    #pragma unroll
    for (int cb = 0; cb < 2; cb++) {
        int ch = cb * 4 + lk;
        f16x8 af0, af1;
        {
            int p0 = ph * 32 + lr;
            af0 = *(const f16x8*)(sl + p0 * 64 + ((ch ^ (p0 & 7)) << 3));
            int p1 = p0 + 16;
            af1 = *(const f16x8*)(sl + p1 * 64 + ((ch ^ (p1 & 7)) << 3));
        }
        #pragma unroll
        for (int i = 0; i < 4; i++) {
            int ofr = oh * 4 + i;
            f16x8 bf = *(const f16x8*)(wfrag + (((size_t)ofr * 2 + cb) * 64 + lane) * 8);
            acc[0][i] = __builtin_amdgcn_mfma_f32_16x16x32_f16(bf, af0, acc[0][i], 0, 0, 0);
            acc[1][i] = __builtin_amdgcn_mfma_f32_16x16x32_f16(bf, af1, acc[1][i], 0, 0, 0);
        }
    }
    #pragma unroll
    for (int i = 0; i < 4; i++) {
        int ofr = oh * 4 + i;
        int cb2 = ofr >> 1;
        int kg = (ofr & 1) * 2 + (lk >> 1);
        int lanep = lr + 16 * kg;
        int sub = lk & 1;
        #pragma unroll
        for (int pf = 0; pf < 2; pf++) {
            f16x4 vv;
            #pragma unroll
            for (int j = 0; j < 4; j++) vv[j] = (_Float16)acc[pf][i][j];
            *(f16x4*)(y2 + (((size_t)(P16 + pf) * 4 + cb2) * 64 + lanep) * 8 + sub * 4) = vv;
        }
        float s[4], q[4];
        #pragma unroll
        for (int j = 0; j < 4; j++) {
            float a0 = acc[0][i][j], a1 = acc[1][i][j];
            s[j] = a0 + a1; q[j] = a0 * a0 + a1 * a1;
        }
        #pragma unroll
        for (int m = 1; m <= 8; m <<= 1)
            #pragma unroll
            for (int j = 0; j < 4; j++) {
                s[j] += __shfl_xor(s[j], m, 64);
                q[j] += __shfl_xor(q[j], m, 64);
            }
        if (lr == 0) {
            int o0 = ofr * 16 + lk * 4;
            float* d = pstat + ((size_t)pb32 * 128 + o0) * 2;
            *(float4*)d = make_float4(s[0], q[0], s[1], q[1]);
            *(float4*)(d + 4) = make_float4(s[2], q[2], s[3], q[3]);
        }
    }
}

// ---------------- fused layer 3: DMA stage + inline GN<128> finalize + swapped GEMM ----------------

__global__ __launch_bounds__(256, 4) void fused_l3(const _Float16* __restrict__ y2,
                                                   const float* __restrict__ pstatIn,
                                                   const float* __restrict__ gn2w,
                                                   const float* __restrict__ gn2b,
                                                   const _Float16* __restrict__ w3f,
                                                   _Float16* __restrict__ y3,
                                                   float* __restrict__ pstatOut) {
    __shared__ _Float16 sl[64 * 128];    // 16 KB A-layout tile
    __shared__ float sstat[256];
    __shared__ float ms[8][2];
    __shared__ _Float16 sscf[128], sshf[128];
    int b = blockIdx.y, pblk = blockIdx.x, tid = threadIdx.x;
    int wv = tid >> 6, lane = tid & 63, lr = lane & 15, lk = lane >> 4;
    int Pg = b * 64 + pblk;
    const _Float16* yt = y2 + (size_t)Pg * 64 * 128;
    #pragma unroll
    for (int i = 0; i < 4; i++) {
        int off = (wv * 4 + i) * 512;    // 1 KB per instruction
        GLOAD_LDS(yt + off + lane * 8, sl + off);
    }
    // inline GN finalize (overlaps DMA): thread owns slot tid = 2c+s
    {
        const float* slab = pstatIn + (size_t)b * 128 * 256;   // 128 pb x 128 c x 2
        float acc = 0.f;
        #pragma unroll 8
        for (int pb = 0; pb < 128; pb++) acc += slab[pb * 256 + tid];
        sstat[tid] = acc;
    }
    __syncthreads();
    if (tid < 8) {
        float S = 0.f, Q = 0.f;
        #pragma unroll
        for (int i = 0; i < 16; i++) {
            int c = tid * 16 + i;
            S += sstat[2 * c]; Q += sstat[2 * c + 1];
        }
        float inv = 1.0f / (16.0f * 4096.0f);
        float mu = S * inv;
        float var = Q * inv - mu * mu;
        if (var < 0.f) var = 0.f;
        ms[tid][0] = mu; ms[tid][1] = rsqrtf(var + 1e-5f);
    }
    __syncthreads();
    if (tid < 128) {
        int g = tid >> 4;
        float ga = gn2w[tid] * ms[g][1];
        sscf[tid] = (_Float16)ga;
        sshf[tid] = (_Float16)(gn2b[tid] - ms[g][0] * ga);
    }
    __syncthreads();   // drains DMA too
    f16x8 scv[4], shv[4];
    #pragma unroll
    for (int cb = 0; cb < 4; cb++) {
        scv[cb] = *(const f16x8*)(sscf + cb * 32 + lk * 8);
        shv[cb] = *(const f16x8*)(sshf + cb * 32 + lk * 8);
    }
    int ph = wv & 1, oh = wv >> 1;
    int pb32 = (Pg << 1) | ph;
    int P16 = Pg * 4 + ph * 2;
    #pragma unroll
    for (int ck = 0; ck < 2; ck++) {
        f32x4 acc[2][4] = {};
        #pragma unroll
        for (int cb = 0; cb < 4; cb++) {
            f16x8 af0 = nrelu(*(const f16x8*)(sl + (((ph * 2 + 0) * 4 + cb) * 64 + lane) * 8), scv[cb], shv[cb]);
            f16x8 af1 = nrelu(*(const f16x8*)(sl + (((ph * 2 + 1) * 4 + cb) * 64 + lane) * 8), scv[cb], shv[cb]);
            #pragma unroll
            for (int i = 0; i < 4; i++) {
                int ofr = oh * 8 + ck * 4 + i;
                f16x8 bf = *(const f16x8*)(w3f + (((size_t)ofr * 4 + cb) * 64 + lane) * 8);
                acc[0][i] = __builtin_amdgcn_mfma_f32_16x16x32_f16(bf, af0, acc[0][i], 0, 0, 0);
                acc[1][i] = __builtin_amdgcn_mfma_f32_16x16x32_f16(bf, af1, acc[1][i], 0, 0, 0);
            }
        }
        #pragma unroll
        for (int i = 0; i < 4; i++) {
            int ofr = oh * 8 + ck * 4 + i;
            int cb3 = ofr >> 1;
            int kg = (ofr & 1) * 2 + (lk >> 1);
            int lanep = lr + 16 * kg;
            int sub = lk & 1;
            #pragma unroll
            for (int pf = 0; pf < 2; pf++) {
                f16x4 vv;
                #pragma unroll
                for (int j = 0; j < 4; j++) vv[j] = (_Float16)acc[pf][i][j];
                *(f16x4*)(y3 + (((size_t)(P16 + pf) * 8 + cb3) * 64 + lanep) * 8 + sub * 4) = vv;
            }
            float s[4], q[4];
            #pragma unroll
            for (int j = 0; j < 4; j++) {
                float a0 = acc[0][i][j], a1 = acc[1][i][j];
                s[j] = a0 + a1; q[j] = a0 * a0 + a1 * a1;
            }
            #pragma unroll
            for (int m = 1; m <= 8; m <<= 1)
                #pragma unroll
                for (int j = 0; j < 4; j++) {
                    s[j] += __shfl_xor(s[j], m, 64);
                    q[j] += __shfl_xor(q[j], m, 64);
                }
            if (lr == 0) {
                int o0 = ofr * 16 + lk * 4;
                float* d = pstatOut + ((size_t)pb32 * 256 + o0) * 2;
                *(float4*)d = make_float4(s[0], q[0], s[1], q[1]);
                *(float4*)(d + 4) = make_float4(s[2], q[2], s[3], q[3]);
            }
        }
    }
}

// ---------------- fused layer 4: DMA stage + inline GN<256> finalize + POOL GEMM ----------------

__global__ __launch_bounds__(256, 4) void fused_l4(const _Float16* __restrict__ y3,
                                                   const float* __restrict__ pstatIn,
                                                   const float* __restrict__ gn3w,
                                                   const float* __restrict__ gn3b,
                                                   const _Float16* __restrict__ w4f,
                                                   float* __restrict__ pstat4) {
    __shared__ _Float16 sl[64 * 256];    // 32 KB A-layout tile
    __shared__ float sstat[512];
    __shared__ float ms[8][2];
    __shared__ _Float16 sscf[256], sshf[256];
    int b = blockIdx.y, pblk = blockIdx.x, tid = threadIdx.x;
    int wv = tid >> 6, lane = tid & 63, lr = lane & 15, lk = lane >> 4;
    int Pg = b * 64 + pblk;
    const _Float16* yt = y3 + (size_t)Pg * 64 * 256;
    #pragma unroll
    for (int i = 0; i < 8; i++) {
        int off = (wv * 8 + i) * 512;    // 1 KB per instruction
        GLOAD_LDS(yt + off + lane * 8, sl + off);
    }
    // inline GN finalize (overlaps DMA): slots tid and tid+256
    {
        const float* slab = pstatIn + (size_t)b * 128 * 512;   // 128 pb x 256 c x 2
        float a0 = 0.f, a1 = 0.f;
        #pragma unroll 8
        for (int pb = 0; pb < 128; pb++) {
            a0 += slab[pb * 512 + tid];
            a1 += slab[pb * 512 + tid + 256];
        }
        sstat[tid] = a0;
        sstat[tid + 256] = a1;
    }
    __syncthreads();
    if (tid < 8) {
        float S = 0.f, Q = 0.f;
        #pragma unroll
        for (int i = 0; i < 32; i++) {
            int c = tid * 32 + i;
            S += sstat[2 * c]; Q += sstat[2 * c + 1];
        }
        float inv = 1.0f / (32.0f * 4096.0f);
        float mu = S * inv;
        float var = Q * inv - mu * mu;
        if (var < 0.f) var = 0.f;
        ms[tid][0] = mu; ms[tid][1] = rsqrtf(var + 1e-5f);
    }
    __syncthreads();
    {
        int g = tid >> 5;
        float ga = gn3w[tid] * ms[g][1];
        sscf[tid] = (_Float16)ga;
        sshf[tid] = (_Float16)(gn3b[tid] - ms[g][0] * ga);
    }
    __syncthreads();   // drains DMA too
    int ph = wv & 1, oh = wv >> 1;
    int pb32 = (Pg << 1) | ph;
    #pragma unroll
    for (int ck = 0; ck < 4; ck++) {
        f32x4 acc[2][4] = {};
        #pragma unroll
        for (int cb = 0; cb < 8; cb++) {
            f16x8 scv = *(const f16x8*)(sscf + cb * 32 + lk * 8);
            f16x8 shv = *(const f16x8*)(sshf + cb * 32 + lk * 8);
            f16x8 af0 = nrelu(*(const f16x8*)(sl + (((ph * 2 + 0) * 8 + cb) * 64 + lane) * 8), scv, shv);
            f16x8 af1 = nrelu(*(const f16x8*)(sl + (((ph * 2 + 1) * 8 + cb) * 64 + lane) * 8), scv, shv);
            #pragma unroll
            for (int i = 0; i < 4; i++) {
                int ofr = oh * 16 + ck * 4 + i;
                f16x8 bf = *(const f16x8*)(w4f + (((size_t)ofr * 8 + cb) * 64 + lane) * 8);
                acc[0][i] = __builtin_amdgcn_mfma_f32_16x16x32_f16(af0, bf, acc[0][i], 0, 0, 0);
                acc[1][i] = __builtin_amdgcn_mfma_f32_16x16x32_f16(af1, bf, acc[1][i], 0, 0, 0);
            }
        }
        #pragma unroll
        for (int i = 0; i < 4; i++) {
            int ofr = oh * 16 + ck * 4 + i;
            float S = 0.f, Q = 0.f, MX = -1e30f, MN = 1e30f;
            #pragma unroll
            for (int pf = 0; pf < 2; pf++)
                #pragma unroll
                for (int j = 0; j < 4; j++) {
                    float v = acc[pf][i][j];
                    S += v; Q += v * v;
                    MX = fmaxf(MX, v); MN = fminf(MN, v);
                }
            S += __shfl_xor(S, 16, 64); Q += __shfl_xor(Q, 16, 64);
            MX = fmaxf(MX, __shfl_xor(MX, 16, 64)); MN = fminf(MN, __shfl_xor(MN, 16, 64));
            S += __shfl_xor(S, 32, 64); Q += __shfl_xor(Q, 32, 64);
            MX = fmaxf(MX, __shfl_xor(MX, 32, 64)); MN = fminf(MN, __shfl_xor(MN, 32, 64));
            if (lk == 0) {
                int o = ofr * 16 + lr;
                *(float4*)(pstat4 + ((size_t)pb32 * 512 + o) * 4) = make_float4(S, Q, MX, MN);
            }
        }
    }
}

// ---------------- pool finalize (coalesced): pstat4[b][128][512][4] -> g[b][512] ----------------

__global__ __launch_bounds__(256) void pool_final(const float* __restrict__ pstat4,
                                                  const float* __restrict__ gamma,
                                                  const float* __restrict__ beta,
                                                  float* __restrict__ g) {
    int b = blockIdx.x >> 3, gr = blockIdx.x & 7;
    int ch = threadIdx.x & 63;
    int pg = threadIdx.x >> 6;          // 4 pb-subgroups
    int o = gr * 64 + ch;
    float S = 0.f, Q = 0.f, MX = -1e30f, MN = 1e30f;
    for (int pb = pg; pb < 128; pb += 4) {
        float4 v = *(const float4*)(pstat4 + (((size_t)(b * 128 + pb)) * 512 + o) * 4);
        S += v.x; Q += v.y; MX = fmaxf(MX, v.z); MN = fminf(MN, v.w);
    }
    __shared__ float sS[4][64], sQ[4][64], sMX[4][64], sMN[4][64];
    sS[pg][ch] = S; sQ[pg][ch] = Q; sMX[pg][ch] = MX; sMN[pg][ch] = MN;
    __syncthreads();
    if (threadIdx.x < 64) {
        float Sc = sS[0][ch] + sS[1][ch] + sS[2][ch] + sS[3][ch];
        float Qc = sQ[0][ch] + sQ[1][ch] + sQ[2][ch] + sQ[3][ch];
        float MXc = fmaxf(fmaxf(sMX[0][ch], sMX[1][ch]), fmaxf(sMX[2][ch], sMX[3][ch]));
        float MNc = fminf(fminf(sMN[0][ch], sMN[1][ch]), fminf(sMN[2][ch], sMN[3][ch]));
        float St = Sc, Qt = Qc;
        for (int off = 32; off; off >>= 1) {
            St += __shfl_xor(St, off, 64);
            Qt += __shfl_xor(Qt, off, 64);
        }
        float inv = 1.0f / (64.0f * 4096.0f);
        float mu = St * inv;
        float var = Qt * inv - mu * mu;
        if (var < 0.f) var = 0.f;
        float rstd = rsqrtf(var + 1e-5f);
        float sc = gamma[o] * rstd;
        float sh = beta[o] - mu * sc;
        float m = (sc >= 0.f ? MXc : MNc) * sc + sh;
        g[b * 512 + o] = fmaxf(m, 0.f);
    }
}

// ---------------- FC head ----------------

__global__ __launch_bounds__(128) void head_kernel(const float* __restrict__ g,
                                                   const float* __restrict__ fc1w,
                                                   const float* __restrict__ fc1b,
                                                   const float* __restrict__ fc2w,
                                                   const float* __restrict__ fc2b,
                                                   float* __restrict__ out) {
    int b = blockIdx.x;
    int o = threadIdx.x;   // 128
    __shared__ float sg[512];
    for (int i = threadIdx.x; i < 512; i += 128) sg[i] = g[b * 512 + i];
    __syncthreads();
    float acc = fc1b[o];
    for (int c = 0; c < 512; c++) acc += sg[c] * fc1w[o * 512 + c];
    float h = fmaxf(acc, 0.f) * fc2w[o];
    for (int off = 32; off; off >>= 1) h += __shfl_down(h, off, 64);
    __shared__ float s2[2];
    if ((threadIdx.x & 63) == 0) s2[threadIdx.x >> 6] = h;
    __syncthreads();
    if (threadIdx.x == 0) out[b] = s2[0] + s2[1] + fc2b[0];
}

// ---------------- launch ----------------

extern "C" void kernel_launch(void* const* d_in, const int* in_sizes, int n_in,
                              void* d_out, int out_size, void* d_ws, size_t ws_size,
                              hipStream_t stream) {
    const float* vol  = (const float*)d_in[0];
    const float* w1   = (const float*)d_in[1];
    const float* gn1w = (const float*)d_in[2];
    const float* gn1b = (const float*)d_in[3];
    const float* w2   = (const float*)d_in[4];
    const float* gn2w = (const float*)d_in[5];
    const float* gn2b = (const float*)d_in[6];
    const float* w3   = (const float*)d_in[7];
    const float* gn3w = (const float*)d_in[8];
    const float* gn3b = (const float*)d_in[9];
    const float* w4   = (const float*)d_in[10];
    const float* gn4w = (const float*)d_in[11];
    const float* gn4b = (const float*)d_in[12];
    const float* fc1w = (const float*)d_in[13];
    const float* fc1b = (const float*)d_in[14];
    const float* fc2w = (const float*)d_in[15];
    const float* fc2b = (const float*)d_in[16];
    float* out = (float*)d_out;

    char* ws = (char*)d_ws;
    size_t cur = 0;
    auto alloc = [&](size_t bytes) -> void* {
        cur = (cur + 255) & ~(size_t)255;
        void* p = ws + cur;
        cur += bytes;
        return p;
    };
    int*      counts  = (int*)alloc((size_t)NB * NCHUNK * 4);
    unsigned long long* bits = (unsigned long long*)alloc((size_t)NB * NCHUNK * 16 * 8);
    float*    pts     = (float*)alloc((size_t)NB * 3 * NPTS * 4);
    float*    gbuf    = (float*)alloc((size_t)NB * 512 * 4);
    float*    pstat1  = (float*)alloc((size_t)NB * 8 * 16 * 2 * 4);
    float*    pstatG  = (float*)alloc((size_t)NB * 128 * 128 * 2 * 4);   // l2 out (C=128)
    float*    pstatG2 = (float*)alloc((size_t)NB * 128 * 256 * 2 * 4);   // l3 out (C=256)
    float*    pstat4  = (float*)alloc((size_t)NB * 128 * 512 * 4 * 4);
    _Float16* w2f     = (_Float16*)alloc((size_t)128 * 64 * 2);
    _Float16* w3f     = (_Float16*)alloc((size_t)256 * 128 * 2);
    _Float16* w4f     = (_Float16*)alloc((size_t)512 * 256 * 2);
    _Float16* y2      = (_Float16*)alloc((size_t)NB * NPTS * 128 * 2);
    _Float16* y3      = (_Float16*)alloc((size_t)NB * NPTS * 256 * 2);

    // 1. count + bitmask (+ appended weight-cast blocks)
    count_cast_kernel<<<dim3(NB * NCHUNK + 84), dim3(256), 0, stream>>>(
        vol, counts, bits, w2, w3, w4, w2f, w3f, w4f);

    // 2. points (inline scan) + fused conv1 stats
    points_kernel<<<dim3(NB * 16), dim3(256), 0, stream>>>(bits, counts, w1, pts, pstat1);

    // 3. layer 2 (inline GN1 finalize, conv1 recompute, swapped GEMM -> y2 A-layout)
    fused_l2<<<dim3(64, NB), dim3(256), 0, stream>>>(pts, w1, pstat1, gn1w, gn1b, w2f, y2, pstatG);

    // 4. layer 3 (DMA stage, inline GN<128> finalize, swapped GEMM -> y3 A-layout)
    fused_l3<<<dim3(64, NB), dim3(256), 0, stream>>>(y2, pstatG, gn2w, gn2b, w3f, y3, pstatG2);

    // 5. layer 4 (DMA stage, inline GN<256> finalize, pooled epilogue)
    fused_l4<<<dim3(64, NB), dim3(256), 0, stream>>>(y3, pstatG2, gn3w, gn3b, w4f, pstat4);

    // 6. pool finalize + head
    pool_final<<<dim3(NB * 8), dim3(256), 0, stream>>>(pstat4, gn4w, gn4b, gbuf);
    head_kernel<<<dim3(NB), dim3(128), 0, stream>>>(gbuf, fc1w, fc1b, fc2w, fc2b, out);
}

// Round 14
// 119.359 us; speedup vs baseline: 1.0738x; 1.0517x over previous
//
#include <hip/hip_runtime.h>
#include <hip/hip_bf16.h>

#define NB 16
#define VOX 884736        // 96*96*96
#define NPTS 4096
#define CHUNK 1024
#define NCHUNK 864        // VOX / CHUNK

typedef _Float16 f16x8 __attribute__((ext_vector_type(8)));
typedef _Float16 f16x4 __attribute__((ext_vector_type(4)));
typedef float f32x4 __attribute__((ext_vector_type(4)));

typedef const __attribute__((address_space(1))) _Float16 gf16;
typedef __attribute__((address_space(3))) _Float16 lf16;
// 16B-per-lane async global->LDS copy: dest = lds base + lane*16 (linear)
#define GLOAD_LDS(gp, lp) __builtin_amdgcn_global_load_lds((gf16*)(gp), (lf16*)(lp), 16, 0, 0)

// packed-fp16 norm + relu on an 8-wide fragment
__device__ __forceinline__ f16x8 nrelu(f16x8 y, f16x8 sc, f16x8 sh) {
    f16x8 r = y * sc + sh;
    #pragma unroll
    for (int e = 0; e < 8; e++) r[e] = (r[e] > (_Float16)0.f) ? r[e] : (_Float16)0.f;
    return r;
}

// ---------------- weight cast helper ----------------

__device__ inline void cast_chunk(const float* __restrict__ wf, _Float16* __restrict__ wh,
                                  int CIN, int t) {
    int lane = t & 63;
    int NCB = CIN / 32;
    int cb = (t >> 6) % NCB;
    int ob = t / (64 * NCB);
    int o = ob * 16 + (lane & 15);
    int c0 = cb * 32 + (lane >> 4) * 8;
    const float* src = wf + (size_t)o * CIN + c0;
    f16x8 v;
    #pragma unroll
    for (int e = 0; e < 8; e++) v[e] = (_Float16)src[e];
    *(f16x8*)(wh + (size_t)t * 8) = v;
}

// ---------------- count + bitmask  (+ appended weight-cast blocks) ----------------

__global__ __launch_bounds__(256) void count_cast_kernel(const float* __restrict__ vol,
                                                         int* __restrict__ counts,
                                                         unsigned long long* __restrict__ bits,
                                                         const float* __restrict__ w2,
                                                         const float* __restrict__ w3,
                                                         const float* __restrict__ w4,
                                                         _Float16* __restrict__ w2f,
                                                         _Float16* __restrict__ w3f,
                                                         _Float16* __restrict__ w4f) {
    if (blockIdx.x >= NB * NCHUNK) {
        int t = (blockIdx.x - NB * NCHUNK) * 256 + threadIdx.x;
        if (t < 1024) cast_chunk(w2, w2f, 64, t);
        else if (t < 1024 + 4096) cast_chunk(w3, w3f, 128, t - 1024);
        else if (t < 1024 + 4096 + 16384) cast_chunk(w4, w4f, 256, t - 5120);
        return;
    }
    int blk = blockIdx.x;  // b*NCHUNK + c
    const float4* v4 = (const float4*)(vol + (size_t)blk * CHUNK);
    float4 v = v4[threadIdx.x];
    int nib = (v.x > 0.5f) | ((v.y > 0.5f) << 1) | ((v.z > 0.5f) << 2) | ((v.w > 0.5f) << 3);
    __shared__ unsigned char nibs[256];
    nibs[threadIdx.x] = (unsigned char)nib;
    int cnt = __popc(nib);
    for (int off = 32; off; off >>= 1) cnt += __shfl_down(cnt, off, 64);
    __shared__ int s[4];
    if ((threadIdx.x & 63) == 0) s[threadIdx.x >> 6] = cnt;
    __syncthreads();
    if (threadIdx.x < 16) {
        unsigned long long wd = 0;
        #pragma unroll
        for (int i = 0; i < 16; i++)
            wd |= (unsigned long long)nibs[threadIdx.x * 16 + i] << (4 * i);
        bits[(size_t)blk * 16 + threadIdx.x] = wd;
    }
    if (threadIdx.x == 0) counts[blk] = s[0] + s[1] + s[2] + s[3];
}

// ---------------- points: inline scan + bitmask rank-select + fused conv1 stats ----------------

__global__ __launch_bounds__(256) void points_kernel(const unsigned long long* __restrict__ bits,
                                                     const int* __restrict__ counts,
                                                     const float* __restrict__ w1,
                                                     float* __restrict__ pts,
                                                     float* __restrict__ pstat1) {
    int b = blockIdx.x >> 4;
    int pc = blockIdx.x & 15;
    int p = pc * 256 + threadIdx.x;
    int tid = threadIdx.x;
    __shared__ int sdat[NCHUNK];
    __shared__ float sw1[192];
    __shared__ int wsum[4];
    for (int i = tid; i < NCHUNK; i += 256) sdat[i] = counts[b * NCHUNK + i];
    if (tid < 192) sw1[tid] = w1[tid];
    __syncthreads();
    // in-block exclusive scan of sdat[0..863]
    int i0 = tid * 4;
    int v0 = (i0 + 0 < NCHUNK) ? sdat[i0 + 0] : 0;
    int v1 = (i0 + 1 < NCHUNK) ? sdat[i0 + 1] : 0;
    int v2 = (i0 + 2 < NCHUNK) ? sdat[i0 + 2] : 0;
    int v3 = (i0 + 3 < NCHUNK) ? sdat[i0 + 3] : 0;
    int l3 = v0 + v1 + v2 + v3;
    int lane = tid & 63, wv = tid >> 6;
    int a = l3;
    #pragma unroll
    for (int off = 1; off < 64; off <<= 1) {
        int x = __shfl_up(a, off, 64);
        if (lane >= off) a += x;
    }
    if (lane == 63) wsum[wv] = a;
    __syncthreads();
    int woff = 0;
    #pragma unroll
    for (int w = 0; w < 4; w++) if (w < wv) woff += wsum[w];
    a += woff;
    int excl = a - l3;
    int n = wsum[0] + wsum[1] + wsum[2] + wsum[3];
    __syncthreads();
    if (i0 + 0 < NCHUNK) sdat[i0 + 0] = excl;
    if (i0 + 1 < NCHUNK) sdat[i0 + 1] = excl + v0;
    if (i0 + 2 < NCHUNK) sdat[i0 + 2] = excl + v0 + v1;
    if (i0 + 3 < NCHUNK) sdat[i0 + 3] = excl + v0 + v1 + v2;
    __syncthreads();
    float px = 0.f, py = 0.f, pz = 0.f;
    if (n > 0) {
        int k;
        if (n >= NPTS) {
            float t = (float)p * ((float)n - 1.0f);
            t = t / 4095.0f;
            k = (int)t;
            if (k > n - 1) k = n - 1;
            if (k < 0) k = 0;
        } else {
            k = p % n;
        }
        int lo = 0, hi = NCHUNK - 1;
        while (lo < hi) {
            int mid = (lo + hi + 1) >> 1;
            if (sdat[mid] <= k) lo = mid; else hi = mid - 1;
        }
        int rr = k - sdat[lo];
        const unsigned long long* wb = bits + ((size_t)b * NCHUNK + lo) * 16;
        unsigned long long chosen = 0;
        int wordidx = 0;
        bool found = false;
        #pragma unroll
        for (int w = 0; w < 16; w++) {
            unsigned long long m = wb[w];
            int pcnt = __popcll(m);
            bool take = (!found) && (rr < pcnt);
            if (take) { chosen = m; wordidx = w; found = true; }
            if (!found) rr -= pcnt;
        }
        int pos = 0;
        unsigned long long m64 = chosen;
        int c = __popcll(m64 & 0xFFFFFFFFull);
        if (rr >= c) { pos = 32; rr -= c; m64 >>= 32; }
        unsigned mm = (unsigned)m64;
        c = __popc(mm & 0xFFFFu); if (rr >= c) { pos += 16; rr -= c; mm >>= 16; }
        c = __popc(mm & 0xFFu);   if (rr >= c) { pos += 8;  rr -= c; mm >>= 8; }
        c = __popc(mm & 0xFu);    if (rr >= c) { pos += 4;  rr -= c; mm >>= 4; }
        c = __popc(mm & 0x3u);    if (rr >= c) { pos += 2;  rr -= c; mm >>= 2; }
        c = mm & 1u;              if (rr >= c) { pos += 1; }
        int flat = lo * CHUNK + wordidx * 64 + pos;
        int dd = flat / 9216;           // 96*96
        int rem = flat - dd * 9216;
        int hh = rem / 96;
        int ww = rem - hh * 96;
        px = (float)dd / 95.0f * 2.0f - 1.0f;
        py = (float)hh / 95.0f * 2.0f - 1.0f;
        pz = (float)ww / 95.0f * 2.0f - 1.0f;
    }
    pts[((size_t)b * 3 + 0) * NPTS + p] = px;
    pts[((size_t)b * 3 + 1) * NPTS + p] = py;
    pts[((size_t)b * 3 + 2) * NPTS + p] = pz;
    // fused conv1 GN partial stats
    float s[8] = {}, q[8] = {};
    #pragma unroll
    for (int o = 0; o < 64; o++) {
        float av = sw1[o * 3 + 0] * px + sw1[o * 3 + 1] * py + sw1[o * 3 + 2] * pz;
        s[o >> 3] += av;
        q[o >> 3] += av * av;
    }
    __shared__ float red[4][8][2];
    #pragma unroll
    for (int g = 0; g < 8; g++) {
        float S = s[g], Q = q[g];
        for (int off = 32; off; off >>= 1) {
            S += __shfl_down(S, off, 64);
            Q += __shfl_down(Q, off, 64);
        }
        if ((threadIdx.x & 63) == 0) { red[wv][g][0] = S; red[wv][g][1] = Q; }
    }
    __syncthreads();
    if (tid < 8) {
        int g = tid;
        float S = red[0][g][0] + red[1][g][0] + red[2][g][0] + red[3][g][0];
        float Q = red[0][g][1] + red[1][g][1] + red[2][g][1] + red[3][g][1];
        float* d = pstat1 + (((size_t)(b * 8 + g)) * 16 + pc) * 2;
        d[0] = S; d[1] = Q;
    }
}

// ---------------- fused layer 2: inline GN1 finalize + conv1 stage + swapped GEMM ----------------

__global__ __launch_bounds__(256, 4) void fused_l2(const float* __restrict__ pts,
                                                   const float* __restrict__ w1,
                                                   const float* __restrict__ pstat1,
                                                   const float* __restrict__ gn1w,
                                                   const float* __restrict__ gn1b,
                                                   const _Float16* __restrict__ wfrag,
                                                   _Float16* __restrict__ y2,
                                                   float* __restrict__ pstat) {
    __shared__ _Float16 sl[64 * 64];
    __shared__ float sw1[192], ssc[64], ssh[64], ms1[8][2];
    int b = blockIdx.y, pblk = blockIdx.x, tid = threadIdx.x;
    if (tid < 192) sw1[tid] = w1[tid];
    if (tid < 8) {
        const float* pbase = pstat1 + (size_t)(b * 8 + tid) * 32;
        float S = 0.f, Q = 0.f;
        #pragma unroll
        for (int pc = 0; pc < 16; pc++) { S += pbase[2 * pc]; Q += pbase[2 * pc + 1]; }
        float inv = 1.0f / (8.0f * 4096.0f);
        float mu = S * inv;
        float var = Q * inv - mu * mu;
        if (var < 0.f) var = 0.f;
        ms1[tid][0] = mu; ms1[tid][1] = rsqrtf(var + 1e-5f);
    }
    __syncthreads();
    if (tid < 64) {
        int g = tid >> 3;
        float ga = gn1w[tid] * ms1[g][1];
        ssc[tid] = ga;
        ssh[tid] = gn1b[tid] - ms1[g][0] * ga;
    }
    __syncthreads();
    {   // stage: recompute conv1 + norm + relu -> swizzled LDS (slot = ch ^ (p&7))
        int p = tid >> 2, qo = (tid & 3) * 16;
        int pg = pblk * 64 + p;
        float x0 = pts[((size_t)b * 3 + 0) * NPTS + pg];
        float x1 = pts[((size_t)b * 3 + 1) * NPTS + pg];
        float x2 = pts[((size_t)b * 3 + 2) * NPTS + pg];
        #pragma unroll
        for (int e = 0; e < 16; e++) {
            int o = qo + e;
            float a = sw1[o * 3 + 0] * x0 + sw1[o * 3 + 1] * x1 + sw1[o * 3 + 2] * x2;
            float r = fmaxf(a * ssc[o] + ssh[o], 0.f);
            sl[p * 64 + (((o >> 3) ^ (p & 7)) << 3) + (o & 7)] = (_Float16)r;
        }
    }
    __syncthreads();
    int wv = tid >> 6, lane = tid & 63, lr = lane & 15, lk = lane >> 4;
    int ph = wv & 1, oh = wv >> 1;
    int Pg = b * 64 + pblk;
    int pb32 = (Pg << 1) | ph;
    int P16 = Pg * 4 + ph * 2;
    f32x4 acc[2][4] = {};
    #pragma unroll
    for (int cb = 0; cb < 2; cb++) {
        int ch = cb * 4 + lk;
        f16x8 af0, af1;
        {
            int p0 = ph * 32 + lr;
            af0 = *(const f16x8*)(sl + p0 * 64 + ((ch ^ (p0 & 7)) << 3));
            int p1 = p0 + 16;
            af1 = *(const f16x8*)(sl + p1 * 64 + ((ch ^ (p1 & 7)) << 3));
        }
        #pragma unroll
        for (int i = 0; i < 4; i++) {
            int ofr = oh * 4 + i;
            f16x8 bf = *(const f16x8*)(wfrag + (((size_t)ofr * 2 + cb) * 64 + lane) * 8);
            acc[0][i] = __builtin_amdgcn_mfma_f32_16x16x32_f16(bf, af0, acc[0][i], 0, 0, 0);
            acc[1][i] = __builtin_amdgcn_mfma_f32_16x16x32_f16(bf, af1, acc[1][i], 0, 0, 0);
        }
    }
    #pragma unroll
    for (int i = 0; i < 4; i++) {
        int ofr = oh * 4 + i;
        int cb2 = ofr >> 1;
        int kg = (ofr & 1) * 2 + (lk >> 1);
        int lanep = lr + 16 * kg;
        int sub = lk & 1;
        #pragma unroll
        for (int pf = 0; pf < 2; pf++) {
            f16x4 vv;
            #pragma unroll
            for (int j = 0; j < 4; j++) vv[j] = (_Float16)acc[pf][i][j];
            *(f16x4*)(y2 + (((size_t)(P16 + pf) * 4 + cb2) * 64 + lanep) * 8 + sub * 4) = vv;
        }
        float s[4], q[4];
        #pragma unroll
        for (int j = 0; j < 4; j++) {
            float a0 = acc[0][i][j], a1 = acc[1][i][j];
            s[j] = a0 + a1; q[j] = a0 * a0 + a1 * a1;
        }
        #pragma unroll
        for (int m = 1; m <= 8; m <<= 1)
            #pragma unroll
            for (int j = 0; j < 4; j++) {
                s[j] += __shfl_xor(s[j], m, 64);
                q[j] += __shfl_xor(q[j], m, 64);
            }
        if (lr == 0) {
            int o0 = ofr * 16 + lk * 4;
            float* d = pstat + ((size_t)pb32 * 128 + o0) * 2;
            *(float4*)d = make_float4(s[0], q[0], s[1], q[1]);
            *(float4*)(d + 4) = make_float4(s[2], q[2], s[3], q[3]);
        }
    }
}

// ---------------- GN finalize: pstat[b][128][C][2] -> fp16 scale/shift ----------------

template <int C>
__global__ __launch_bounds__(256) void gn_finalizeG(const float* __restrict__ pstat,
                                                    const float* __restrict__ gamma,
                                                    const float* __restrict__ beta,
                                                    _Float16* __restrict__ scaleh,
                                                    _Float16* __restrict__ shifth) {
    constexpr int GS = C / 8;
    int b = blockIdx.x >> 3, g = blockIdx.x & 7;
    const float* base = pstat + (size_t)b * 128 * C * 2;
    float S = 0.f, Q = 0.f;
    for (int i = threadIdx.x; i < 128 * GS; i += 256) {
        int pb = i / GS;
        int c = g * GS + (i % GS);
        const float* d = base + ((size_t)pb * C + c) * 2;
        S += d[0]; Q += d[1];
    }
    for (int off = 32; off; off >>= 1) {
        S += __shfl_down(S, off, 64);
        Q += __shfl_down(Q, off, 64);
    }
    __shared__ float ss[8];
    if ((threadIdx.x & 63) == 0) {
        ss[(threadIdx.x >> 6) * 2] = S;
        ss[(threadIdx.x >> 6) * 2 + 1] = Q;
    }
    __syncthreads();
    __shared__ float ms[2];
    if (threadIdx.x == 0) {
        float St = ss[0] + ss[2] + ss[4] + ss[6];
        float Qt = ss[1] + ss[3] + ss[5] + ss[7];
        float inv = 1.0f / ((float)GS * 4096.0f);
        float mu = St * inv;
        float var = Qt * inv - mu * mu;
        if (var < 0.f) var = 0.f;
        ms[0] = mu; ms[1] = rsqrtf(var + 1e-5f);
    }
    __syncthreads();
    for (int i = threadIdx.x; i < GS; i += 256) {
        int c = g * GS + i;
        float ga = gamma[c] * ms[1];
        scaleh[(size_t)b * C + c] = (_Float16)ga;
        shifth[(size_t)b * C + c] = (_Float16)(beta[c] - ms[0] * ga);
    }
}

// ---------------- fused layer 3: DMA stage + normalize-once + swapped GEMM ----------------

__global__ __launch_bounds__(256, 4) void fused_l3(const _Float16* __restrict__ y2,
                                                   const _Float16* __restrict__ sch,
                                                   const _Float16* __restrict__ shh,
                                                   const _Float16* __restrict__ w3f,
                                                   _Float16* __restrict__ y3,
                                                   float* __restrict__ pstatOut) {
    __shared__ _Float16 sl[64 * 128];    // 16 KB A-layout tile
    __shared__ _Float16 sscf[128], sshf[128];
    int b = blockIdx.y, pblk = blockIdx.x, tid = threadIdx.x;
    int wv = tid >> 6, lane = tid & 63, lr = lane & 15, lk = lane >> 4;
    int Pg = b * 64 + pblk;
    const _Float16* yt = y2 + (size_t)Pg * 64 * 128;
    #pragma unroll
    for (int i = 0; i < 4; i++) {
        int off = (wv * 4 + i) * 512;    // 1 KB per instruction
        GLOAD_LDS(yt + off + lane * 8, sl + off);
    }
    if (tid < 128) {
        sscf[tid] = sch[b * 128 + tid];
        sshf[tid] = shh[b * 128 + tid];
    }
    __syncthreads();   // drains DMA + sscf
    // normalize-once in place: 4 chunks per thread (2-way LDS access, free)
    #pragma unroll
    for (int k = 0; k < 4; k++) {
        int q = tid + k * 256;           // f16x8 chunk id
        int ln = q & 63;
        int cb = (q >> 6) & 3;
        int c0 = cb * 32 + (ln >> 4) * 8;
        f16x8 v = *(const f16x8*)(sl + (size_t)q * 8);
        f16x8 scv = *(const f16x8*)(sscf + c0);
        f16x8 shv = *(const f16x8*)(sshf + c0);
        *(f16x8*)(sl + (size_t)q * 8) = nrelu(v, scv, shv);
    }
    __syncthreads();
    int ph = wv & 1, oh = wv >> 1;
    int pb32 = (Pg << 1) | ph;
    int P16 = Pg * 4 + ph * 2;
    #pragma unroll
    for (int ck = 0; ck < 2; ck++) {
        f32x4 acc[2][4] = {};
        #pragma unroll
        for (int cb = 0; cb < 4; cb++) {
            f16x8 af0 = *(const f16x8*)(sl + (((ph * 2 + 0) * 4 + cb) * 64 + lane) * 8);
            f16x8 af1 = *(const f16x8*)(sl + (((ph * 2 + 1) * 4 + cb) * 64 + lane) * 8);
            #pragma unroll
            for (int i = 0; i < 4; i++) {
                int ofr = oh * 8 + ck * 4 + i;
                f16x8 bf = *(const f16x8*)(w3f + (((size_t)ofr * 4 + cb) * 64 + lane) * 8);
                acc[0][i] = __builtin_amdgcn_mfma_f32_16x16x32_f16(bf, af0, acc[0][i], 0, 0, 0);
                acc[1][i] = __builtin_amdgcn_mfma_f32_16x16x32_f16(bf, af1, acc[1][i], 0, 0, 0);
            }
        }
        #pragma unroll
        for (int i = 0; i < 4; i++) {
            int ofr = oh * 8 + ck * 4 + i;
            int cb3 = ofr >> 1;
            int kg = (ofr & 1) * 2 + (lk >> 1);
            int lanep = lr + 16 * kg;
            int sub = lk & 1;
            #pragma unroll
            for (int pf = 0; pf < 2; pf++) {
                f16x4 vv;
                #pragma unroll
                for (int j = 0; j < 4; j++) vv[j] = (_Float16)acc[pf][i][j];
                *(f16x4*)(y3 + (((size_t)(P16 + pf) * 8 + cb3) * 64 + lanep) * 8 + sub * 4) = vv;
            }
            float s[4], q[4];
            #pragma unroll
            for (int j = 0; j < 4; j++) {
                float a0 = acc[0][i][j], a1 = acc[1][i][j];
                s[j] = a0 + a1; q[j] = a0 * a0 + a1 * a1;
            }
            #pragma unroll
            for (int m = 1; m <= 8; m <<= 1)
                #pragma unroll
                for (int j = 0; j < 4; j++) {
                    s[j] += __shfl_xor(s[j], m, 64);
                    q[j] += __shfl_xor(q[j], m, 64);
                }
            if (lr == 0) {
                int o0 = ofr * 16 + lk * 4;
                float* d = pstatOut + ((size_t)pb32 * 256 + o0) * 2;
                *(float4*)d = make_float4(s[0], q[0], s[1], q[1]);
                *(float4*)(d + 4) = make_float4(s[2], q[2], s[3], q[3]);
            }
        }
    }
}

// ---------------- fused layer 4: DMA stage + normalize-once + POOL GEMM ----------------

__global__ __launch_bounds__(256, 4) void fused_l4(const _Float16* __restrict__ y3,
                                                   const _Float16* __restrict__ sch,
                                                   const _Float16* __restrict__ shh,
                                                   const _Float16* __restrict__ w4f,
                                                   float* __restrict__ pstat4) {
    __shared__ _Float16 sl[64 * 256];    // 32 KB A-layout tile
    __shared__ _Float16 sscf[256], sshf[256];
    int b = blockIdx.y, pblk = blockIdx.x, tid = threadIdx.x;
    int wv = tid >> 6, lane = tid & 63, lr = lane & 15, lk = lane >> 4;
    int Pg = b * 64 + pblk;
    const _Float16* yt = y3 + (size_t)Pg * 64 * 256;
    #pragma unroll
    for (int i = 0; i < 8; i++) {
        int off = (wv * 8 + i) * 512;    // 1 KB per instruction
        GLOAD_LDS(yt + off + lane * 8, sl + off);
    }
    sscf[tid] = sch[b * 256 + tid];
    sshf[tid] = shh[b * 256 + tid];
    __syncthreads();   // drains DMA + sscf
    // normalize-once in place: 8 chunks per thread
    #pragma unroll
    for (int k = 0; k < 8; k++) {
        int q = tid + k * 256;           // f16x8 chunk id
        int ln = q & 63;
        int cb = (q >> 6) & 7;
        int c0 = cb * 32 + (ln >> 4) * 8;
        f16x8 v = *(const f16x8*)(sl + (size_t)q * 8);
        f16x8 scv = *(const f16x8*)(sscf + c0);
        f16x8 shv = *(const f16x8*)(sshf + c0);
        *(f16x8*)(sl + (size_t)q * 8) = nrelu(v, scv, shv);
    }
    __syncthreads();
    int ph = wv & 1, oh = wv >> 1;
    int pb32 = (Pg << 1) | ph;
    #pragma unroll
    for (int ck = 0; ck < 4; ck++) {
        f32x4 acc[2][4] = {};
        #pragma unroll
        for (int cb = 0; cb < 8; cb++) {
            f16x8 af0 = *(const f16x8*)(sl + (((ph * 2 + 0) * 8 + cb) * 64 + lane) * 8);
            f16x8 af1 = *(const f16x8*)(sl + (((ph * 2 + 1) * 8 + cb) * 64 + lane) * 8);
            #pragma unroll
            for (int i = 0; i < 4; i++) {
                int ofr = oh * 16 + ck * 4 + i;
                f16x8 bf = *(const f16x8*)(w4f + (((size_t)ofr * 8 + cb) * 64 + lane) * 8);
                acc[0][i] = __builtin_amdgcn_mfma_f32_16x16x32_f16(af0, bf, acc[0][i], 0, 0, 0);
                acc[1][i] = __builtin_amdgcn_mfma_f32_16x16x32_f16(af1, bf, acc[1][i], 0, 0, 0);
            }
        }
        #pragma unroll
        for (int i = 0; i < 4; i++) {
            int ofr = oh * 16 + ck * 4 + i;
            float S = 0.f, Q = 0.f, MX = -1e30f, MN = 1e30f;
            #pragma unroll
            for (int pf = 0; pf < 2; pf++)
                #pragma unroll
                for (int j = 0; j < 4; j++) {
                    float v = acc[pf][i][j];
                    S += v; Q += v * v;
                    MX = fmaxf(MX, v); MN = fminf(MN, v);
                }
            S += __shfl_xor(S, 16, 64); Q += __shfl_xor(Q, 16, 64);
            MX = fmaxf(MX, __shfl_xor(MX, 16, 64)); MN = fminf(MN, __shfl_xor(MN, 16, 64));
            S += __shfl_xor(S, 32, 64); Q += __shfl_xor(Q, 32, 64);
            MX = fmaxf(MX, __shfl_xor(MX, 32, 64)); MN = fminf(MN, __shfl_xor(MN, 32, 64));
            if (lk == 0) {
                int o = ofr * 16 + lr;
                *(float4*)(pstat4 + ((size_t)pb32 * 512 + o) * 4) = make_float4(S, Q, MX, MN);
            }
        }
    }
}

// ---------------- pool finalize (coalesced): pstat4[b][128][512][4] -> g[b][512] ----------------

__global__ __launch_bounds__(256) void pool_final(const float* __restrict__ pstat4,
                                                  const float* __restrict__ gamma,
                                                  const float* __restrict__ beta,
                                                  float* __restrict__ g) {
    int b = blockIdx.x >> 3, gr = blockIdx.x & 7;
    int ch = threadIdx.x & 63;
    int pg = threadIdx.x >> 6;          // 4 pb-subgroups
    int o = gr * 64 + ch;
    float S = 0.f, Q = 0.f, MX = -1e30f, MN = 1e30f;
    for (int pb = pg; pb < 128; pb += 4) {
        float4 v = *(const float4*)(pstat4 + (((size_t)(b * 128 + pb)) * 512 + o) * 4);
        S += v.x; Q += v.y; MX = fmaxf(MX, v.z); MN = fminf(MN, v.w);
    }
    __shared__ float sS[4][64], sQ[4][64], sMX[4][64], sMN[4][64];
    sS[pg][ch] = S; sQ[pg][ch] = Q; sMX[pg][ch] = MX; sMN[pg][ch] = MN;
    __syncthreads();
    if (threadIdx.x < 64) {
        float Sc = sS[0][ch] + sS[1][ch] + sS[2][ch] + sS[3][ch];
        float Qc = sQ[0][ch] + sQ[1][ch] + sQ[2][ch] + sQ[3][ch];
        float MXc = fmaxf(fmaxf(sMX[0][ch], sMX[1][ch]), fmaxf(sMX[2][ch], sMX[3][ch]));
        float MNc = fminf(fminf(sMN[0][ch], sMN[1][ch]), fminf(sMN[2][ch], sMN[3][ch]));
        float St = Sc, Qt = Qc;
        for (int off = 32; off; off >>= 1) {
            St += __shfl_xor(St, off, 64);
            Qt += __shfl_xor(Qt, off, 64);
        }
        float inv = 1.0f / (64.0f * 4096.0f);
        float mu = St * inv;
        float var = Qt * inv - mu * mu;
        if (var < 0.f) var = 0.f;
        float rstd = rsqrtf(var + 1e-5f);
        float sc = gamma[o] * rstd;
        float sh = beta[o] - mu * sc;
        float m = (sc >= 0.f ? MXc : MNc) * sc + sh;
        g[b * 512 + o] = fmaxf(m, 0.f);
    }
}

// ---------------- FC head ----------------

__global__ __launch_bounds__(128) void head_kernel(const float* __restrict__ g,
                                                   const float* __restrict__ fc1w,
                                                   const float* __restrict__ fc1b,
                                                   const float* __restrict__ fc2w,
                                                   const float* __restrict__ fc2b,
                                                   float* __restrict__ out) {
    int b = blockIdx.x;
    int o = threadIdx.x;   // 128
    __shared__ float sg[512];
    for (int i = threadIdx.x; i < 512; i += 128) sg[i] = g[b * 512 + i];
    __syncthreads();
    float acc = fc1b[o];
    for (int c = 0; c < 512; c++) acc += sg[c] * fc1w[o * 512 + c];
    float h = fmaxf(acc, 0.f) * fc2w[o];
    for (int off = 32; off; off >>= 1) h += __shfl_down(h, off, 64);
    __shared__ float s2[2];
    if ((threadIdx.x & 63) == 0) s2[threadIdx.x >> 6] = h;
    __syncthreads();
    if (threadIdx.x == 0) out[b] = s2[0] + s2[1] + fc2b[0];
}

// ---------------- launch ----------------

extern "C" void kernel_launch(void* const* d_in, const int* in_sizes, int n_in,
                              void* d_out, int out_size, void* d_ws, size_t ws_size,
                              hipStream_t stream) {
    const float* vol  = (const float*)d_in[0];
    const float* w1   = (const float*)d_in[1];
    const float* gn1w = (const float*)d_in[2];
    const float* gn1b = (const float*)d_in[3];
    const float* w2   = (const float*)d_in[4];
    const float* gn2w = (const float*)d_in[5];
    const float* gn2b = (const float*)d_in[6];
    const float* w3   = (const float*)d_in[7];
    const float* gn3w = (const float*)d_in[8];
    const float* gn3b = (const float*)d_in[9];
    const float* w4   = (const float*)d_in[10];
    const float* gn4w = (const float*)d_in[11];
    const float* gn4b = (const float*)d_in[12];
    const float* fc1w = (const float*)d_in[13];
    const float* fc1b = (const float*)d_in[14];
    const float* fc2w = (const float*)d_in[15];
    const float* fc2b = (const float*)d_in[16];
    float* out = (float*)d_out;

    char* ws = (char*)d_ws;
    size_t cur = 0;
    auto alloc = [&](size_t bytes) -> void* {
        cur = (cur + 255) & ~(size_t)255;
        void* p = ws + cur;
        cur += bytes;
        return p;
    };
    int*      counts  = (int*)alloc((size_t)NB * NCHUNK * 4);
    unsigned long long* bits = (unsigned long long*)alloc((size_t)NB * NCHUNK * 16 * 8);
    float*    pts     = (float*)alloc((size_t)NB * 3 * NPTS * 4);
    float*    gbuf    = (float*)alloc((size_t)NB * 512 * 4);
    float*    pstat1  = (float*)alloc((size_t)NB * 8 * 16 * 2 * 4);
    float*    pstatG  = (float*)alloc((size_t)NB * 128 * 128 * 2 * 4);   // l2 out (C=128)
    float*    pstatG2 = (float*)alloc((size_t)NB * 128 * 256 * 2 * 4);   // l3 out (C=256)
    float*    pstat4  = (float*)alloc((size_t)NB * 128 * 512 * 4 * 4);
    _Float16* sc2h    = (_Float16*)alloc((size_t)NB * 128 * 2);
    _Float16* sh2h    = (_Float16*)alloc((size_t)NB * 128 * 2);
    _Float16* sc3h    = (_Float16*)alloc((size_t)NB * 256 * 2);
    _Float16* sh3h    = (_Float16*)alloc((size_t)NB * 256 * 2);
    _Float16* w2f     = (_Float16*)alloc((size_t)128 * 64 * 2);
    _Float16* w3f     = (_Float16*)alloc((size_t)256 * 128 * 2);
    _Float16* w4f     = (_Float16*)alloc((size_t)512 * 256 * 2);
    _Float16* y2      = (_Float16*)alloc((size_t)NB * NPTS * 128 * 2);
    _Float16* y3      = (_Float16*)alloc((size_t)NB * NPTS * 256 * 2);

    // 1. count + bitmask (+ appended weight-cast blocks)
    count_cast_kernel<<<dim3(NB * NCHUNK + 84), dim3(256), 0, stream>>>(
        vol, counts, bits, w2, w3, w4, w2f, w3f, w4f);

    // 2. points (inline scan) + fused conv1 stats
    points_kernel<<<dim3(NB * 16), dim3(256), 0, stream>>>(bits, counts, w1, pts, pstat1);

    // 3. layer 2 (inline GN1 finalize, conv1 recompute, swapped GEMM -> y2 A-layout)
    fused_l2<<<dim3(64, NB), dim3(256), 0, stream>>>(pts, w1, pstat1, gn1w, gn1b, w2f, y2, pstatG);

    // 4. layer 3 (tiny GN finalize, then DMA stage + normalize-once + swapped GEMM)
    gn_finalizeG<128><<<dim3(NB * 8), dim3(256), 0, stream>>>(pstatG, gn2w, gn2b, sc2h, sh2h);
    fused_l3<<<dim3(64, NB), dim3(256), 0, stream>>>(y2, sc2h, sh2h, w3f, y3, pstatG2);

    // 5. layer 4 (tiny GN finalize, then DMA stage + normalize-once + pooled epilogue)
    gn_finalizeG<256><<<dim3(NB * 8), dim3(256), 0, stream>>>(pstatG2, gn3w, gn3b, sc3h, sh3h);
    fused_l4<<<dim3(64, NB), dim3(256), 0, stream>>>(y3, sc3h, sh3h, w4f, pstat4);

    // 6. pool finalize + head
    pool_final<<<dim3(NB * 8), dim3(256), 0, stream>>>(pstat4, gn4w, gn4b, gbuf);
    head_kernel<<<dim3(NB), dim3(128), 0, stream>>>(gbuf, fc1w, fc1b, fc2w, fc2b, out);
}